// Round 11
// baseline (279.465 us; speedup 1.0000x reference)
//
#include <hip/hip_runtime.h>
#include <hip/hip_bf16.h>
#include <math.h>

typedef __attribute__((ext_vector_type(4))) float f32x4;
typedef __attribute__((ext_vector_type(8))) short s16x8;
typedef __attribute__((ext_vector_type(4))) short s16x4;

static __device__ __forceinline__ float sigmoidf_(float v) { return 1.0f / (1.0f + __expf(-v)); }
static __device__ __forceinline__ unsigned short f2bf(float f) {
  unsigned u = __float_as_uint(f);
  u += 0x7fffu + ((u >> 16) & 1u);
  return (unsigned short)(u >> 16);
}
static __device__ __forceinline__ float bf2f(unsigned short h) {
  return __uint_as_float(((unsigned)h) << 16);
}
static __device__ __forceinline__ s16x4 pk4(float a, float b, float c, float d) {
  union { __hip_bfloat162 h2[2]; s16x4 v; } u;
  u.h2[0] = __float22bfloat162_rn(make_float2(a, b));
  u.h2[1] = __float22bfloat162_rn(make_float2(c, d));
  return u.v;
}
static __device__ __forceinline__ s16x8 pk8(const float* f) {
  union { __hip_bfloat162 h2[4]; s16x8 v; } u;
  u.h2[0] = __float22bfloat162_rn(make_float2(f[0], f[1]));
  u.h2[1] = __float22bfloat162_rn(make_float2(f[2], f[3]));
  u.h2[2] = __float22bfloat162_rn(make_float2(f[4], f[5]));
  u.h2[3] = __float22bfloat162_rn(make_float2(f[6], f[7]));
  return u.v;
}

// K0: weight prep (blocks 0..71) + tproj (blocks 72..75).
__global__ __launch_bounds__(256) void prep_misc(const float* __restrict__ cw,
                                                 const float* __restrict__ gw,
                                                 const float* __restrict__ t,
                                                 const float* __restrict__ tw,
                                                 const float* __restrict__ tb,
                                                 unsigned short* __restrict__ wcb,
                                                 unsigned short* __restrict__ wgb,
                                                 float* __restrict__ tpo) {
  int blk = blockIdx.x;
  if (blk < 72) {
    int i = blk * 256 + threadIdx.x;
    if (i < 9216) {   // conv_w [o][c][3][3] -> wcb[tap][o][c=32]
      int tap = i >> 10, rem = i & 1023, o = rem >> 5, c = rem & 31;
      wcb[i] = f2bf(cw[(o * 32 + c) * 9 + tap]);
    }
    if (i < 18432) {  // gate_w [o][ic][3][3] -> wgb[tap][o][ic=64]
      int tap = i >> 11, rem = i & 2047, o = rem >> 6, c = rem & 63;
      wgb[i] = f2bf(gw[(o * 64 + c) * 9 + tap]);
    }
  } else {
    int idx = (blk - 72) * 256 + threadIdx.x;  // < 1024
    int b = idx >> 6, j = idx & 63;
    const float* tr = t + b * 256;
    const float* wr = tw + j * 256;
    float s = tb[j];
    for (int k = 0; k < 256; ++k) s = fmaf(tr[k], wr[k], s);
    tpo[idx] = s;
  }
}

// K1 (R10): conv3x3 MFMA (A=weights, B=pixels), 256 threads, pipelined weights.
__global__ __launch_bounds__(256) void conv1_mfma(const float* __restrict__ x,
                                                  const unsigned short* __restrict__ wcb,
                                                  const float* __restrict__ conv_b,
                                                  unsigned short* __restrict__ ycl,
                                                  float* __restrict__ stats,
                                                  float* __restrict__ nodes) {
  __shared__ alignas(16) unsigned short xt[324 * 32];  // [s][c] bf16, swizzled
  __shared__ float gpart[8][2][4];
  int blk = blockIdx.x;
  int b = blk >> 8, r = blk & 255, gy = r >> 4, gx = r & 15;
  int tid = threadIdx.x;
  int y0 = gy * 16 - 1, x0 = gx * 16 - 1;
  for (int i = tid; i < 2592; i += 256) {
    int q = i / 324, s = i - q * 324;
    int row = s / 18, col = s - row * 18;
    int yy = y0 + row, xx = x0 + col;
    float v0 = 0, v1 = 0, v2 = 0, v3 = 0;
    if ((unsigned)yy < 256u && (unsigned)xx < 256u) {
      const float* p = x + ((size_t)(b * 32 + q * 4)) * 65536 + yy * 256 + xx;
      v0 = p[0]; v1 = p[65536]; v2 = p[131072]; v3 = p[196608];
    }
    int slot = (q >> 1) ^ (s & 3) ^ ((s >> 2) & 3);
    int off = s * 32 + slot * 8 + (q & 1) * 4;
    *(s16x4*)&xt[off] = pk4(v0, v1, v2, v3);
  }
  __syncthreads();

  int wv = tid >> 6, lane = tid & 63;
  int lr = lane & 15, lg = lane >> 4;

  // fused patch means
#pragma unroll
  for (int cc = 0; cc < 8; ++cc) {
    int c = wv * 8 + cc;
    int q = c >> 2, jj = c & 3;
    float s = 0.f;
#pragma unroll
    for (int pp = 0; pp < 4; ++pp) {
      int p = lane * 4 + pp;
      int sp = ((p >> 4) + 1) * 18 + (p & 15) + 1;
      int off = sp * 32 + (((q >> 1) ^ (sp & 3) ^ ((sp >> 2) & 3)) << 3) + (q & 1) * 4 + jj;
      s += bf2f(xt[off]);
    }
    for (int m = 1; m < 64; m <<= 1) s += __shfl_xor(s, m);
    if (lane == 0) nodes[(size_t)blk * 34 + c] = s * (1.f / 256.f);
  }
  if (tid == 0) {
    nodes[(size_t)blk * 34 + 32] = (float)gy * (1.f / 16.f);
    nodes[(size_t)blk * 34 + 33] = (float)gx * (1.f / 16.f);
  }

  // MFMA: D row(lg*4+rr)=o, col(lr)=px. 2-stage weight pipeline.
  f32x4 acc[4][2];
  f32x4 cb0 = *(const f32x4*)&conv_b[lg * 4];
  f32x4 cb1 = *(const f32x4*)&conv_b[16 + lg * 4];
#pragma unroll
  for (int mi = 0; mi < 4; ++mi) { acc[mi][0] = cb0; acc[mi][1] = cb1; }

  s16x8 wc0 = *(const s16x8*)&wcb[lr * 32 + lg * 8];
  s16x8 wc1 = *(const s16x8*)&wcb[(16 + lr) * 32 + lg * 8];
#pragma unroll
  for (int tap = 0; tap < 9; ++tap) {
    s16x8 wn0 = wc0, wn1 = wc1;
    if (tap < 8) {
      wn0 = *(const s16x8*)&wcb[(tap + 1) * 1024 + lr * 32 + lg * 8];
      wn1 = *(const s16x8*)&wcb[(tap + 1) * 1024 + (16 + lr) * 32 + lg * 8];
    }
    int ky = tap / 3, kx = tap - ky * 3;
#pragma unroll
    for (int mi = 0; mi < 4; ++mi) {
      int s = (wv * 4 + mi + ky) * 18 + lr + kx;
      int offB = s * 32 + ((lg ^ (s & 3) ^ ((s >> 2) & 3)) << 3);
      s16x8 xf = *(const s16x8*)&xt[offB];
      acc[mi][0] = __builtin_amdgcn_mfma_f32_16x16x32_bf16(wc0, xf, acc[mi][0], 0, 0, 0);
      acc[mi][1] = __builtin_amdgcn_mfma_f32_16x16x32_bf16(wc1, xf, acc[mi][1], 0, 0, 0);
    }
    wc0 = wn0; wc1 = wn1;
  }
  // epilogue: channel-last store
#pragma unroll
  for (int mi = 0; mi < 4; ++mi) {
    int oy = gy * 16 + wv * 4 + mi;
    size_t pixbase = ((size_t)b * 65536 + (size_t)oy * 256 + gx * 16 + lr) * 32;
#pragma unroll
    for (int nt = 0; nt < 2; ++nt) {
      f32x4 a = acc[mi][nt];
      *(s16x4*)&ycl[pixbase + nt * 16 + lg * 4] = pk4(a[0], a[1], a[2], a[3]);
    }
  }
  // fused GN stats: group g = nt*4+lg
#pragma unroll
  for (int nt = 0; nt < 2; ++nt) {
    float s = 0.f, q = 0.f;
#pragma unroll
    for (int mi = 0; mi < 4; ++mi)
#pragma unroll
      for (int rr = 0; rr < 4; ++rr) {
        float v = acc[mi][nt][rr];
        s += v; q += v * v;
      }
    for (int m = 1; m < 16; m <<= 1) { s += __shfl_xor(s, m); q += __shfl_xor(q, m); }
    if (lr == 0) { gpart[nt * 4 + lg][0][wv] = s; gpart[nt * 4 + lg][1][wv] = q; }
  }
  __syncthreads();
  if (tid < 16) {
    int g = tid >> 1, which = tid & 1;
    float v = gpart[g][which][0] + gpart[g][which][1] + gpart[g][which][2] + gpart[g][which][3];
    atomicAdd(&stats[(which ? 128 : 0) + b * 8 + g], v);
  }
}

// K2: fold GN into per-(b,c) scale/shift
__global__ void gn_finalize(const float* __restrict__ stats,
                            const float* __restrict__ gn_g,
                            const float* __restrict__ gn_b,
                            float* __restrict__ mrs) {
  int i = threadIdx.x;  // 512
  int b = i >> 5, c = i & 31, g = c >> 2;
  float s = stats[b * 8 + g], q = stats[128 + b * 8 + g];
  const float n = 262144.f;
  float mean = s / n;
  float var = q / n - mean * mean;
  float rs = rsqrtf(var + 1e-5f);
  float scale = rs * gn_g[c];
  mrs[i] = scale;
  mrs[512 + i] = gn_b[c] - mean * scale;
}

__device__ __forceinline__ float dinv_at(int gy, int gx) {
  return rsqrtf((float)(1 + (gy > 0) + (gy < 15) + (gx > 0) + (gx < 15)));
}

// K3: fused GCN: h = nodes@gcn_w (self+4 nbrs), Kipf prop, bias, LN.
__global__ __launch_bounds__(64) void gcn_fused(const float* __restrict__ nodes,
                                                const float* __restrict__ gw,
                                                const float* __restrict__ gcn_b,
                                                const float* __restrict__ ln_g,
                                                const float* __restrict__ ln_b,
                                                float* __restrict__ lnout) {
  int n = blockIdx.x * 2 + (threadIdx.x >> 5);
  int o = threadIdx.x & 31;
  int r = n & 255, gy = r >> 4, gx = r & 15;
  float dn = dinv_at(gy, gx);
  float s = 0.f;
  {
    const float* nr = nodes + (size_t)n * 34;
    float hh = 0.f;
#pragma unroll
    for (int k = 0; k < 34; ++k) hh = fmaf(nr[k], gw[k * 32 + o], hh);
    s = hh * dn;
  }
  if (gy > 0) {
    const float* nr = nodes + (size_t)(n - 16) * 34;
    float hh = 0.f;
#pragma unroll
    for (int k = 0; k < 34; ++k) hh = fmaf(nr[k], gw[k * 32 + o], hh);
    s += hh * dinv_at(gy - 1, gx);
  }
  if (gy < 15) {
    const float* nr = nodes + (size_t)(n + 16) * 34;
    float hh = 0.f;
#pragma unroll
    for (int k = 0; k < 34; ++k) hh = fmaf(nr[k], gw[k * 32 + o], hh);
    s += hh * dinv_at(gy + 1, gx);
  }
  if (gx > 0) {
    const float* nr = nodes + (size_t)(n - 1) * 34;
    float hh = 0.f;
#pragma unroll
    for (int k = 0; k < 34; ++k) hh = fmaf(nr[k], gw[k * 32 + o], hh);
    s += hh * dinv_at(gy, gx - 1);
  }
  if (gx < 15) {
    const float* nr = nodes + (size_t)(n + 1) * 34;
    float hh = 0.f;
#pragma unroll
    for (int k = 0; k < 34; ++k) hh = fmaf(nr[k], gw[k * 32 + o], hh);
    s += hh * dinv_at(gy, gx + 1);
  }
  float g = dn * s + gcn_b[o];
  float mu = g;
  for (int m = 16; m; m >>= 1) mu += __shfl_xor(mu, m);
  mu *= (1.0f / 32.0f);
  float d = g - mu;
  float v = d * d;
  for (int m = 16; m; m >>= 1) v += __shfl_xor(v, m);
  v *= (1.0f / 32.0f);
  lnout[n * 32 + o] = d * rsqrtf(v + 1e-5f) * ln_g[o] + ln_b[o];
}

// K6: k-split 2-phase gate conv (24.2KB LDS). R11: NO min-waves forcing —
// plain launch_bounds(256); compiler picks VGPR (~90-100), LDS gives 5-6
// blocks/CU naturally. (R8 forced 5 waves->VGPR 48->spill; R9 forced 4->64->spill.)
__global__ __launch_bounds__(256) void fused_gate_mfma(
    const unsigned short* __restrict__ ycl, const float* __restrict__ mrs,
    const float* __restrict__ lnf, const unsigned short* __restrict__ wgb,
    const float* __restrict__ gate_b, const float* __restrict__ tpv,
    float* __restrict__ out) {
  __shared__ alignas(16) unsigned short comb[324 * 32];   // one 32-ch half, swizzled
  __shared__ alignas(16) unsigned short vvb[18 * 3 * 32]; // vertical-interp, bf16
  int blk = blockIdx.x;
  int b = blk >> 8, r = blk & 255, gy = r >> 4, gx = r & 15;
  int tid = threadIdx.x;
  int wv = tid >> 6, lane = tid & 63;
  int lr = lane & 15, lg = lane >> 4;
  int y0 = gy * 16 - 1, x0 = gx * 16 - 1;
  const s16x8 z8 = (s16x8){0, 0, 0, 0, 0, 0, 0, 0};

  // ---- phase A staging: conv half (GN+SiLU on load) + vv (bf16) ----
  int i0 = tid, i1 = tid + 256;
  int row0 = i0 / 18, col0 = i0 - row0 * 18;
  int yy0_ = y0 + row0, xx0_ = x0 + col0;
  bool in0 = ((unsigned)yy0_ < 256u) && ((unsigned)xx0_ < 256u);
  int row1 = i1 / 18, col1 = i1 - row1 * 18;
  int yy1_ = y0 + row1, xx1_ = x0 + col1;
  bool in1 = (i1 < 324) && ((unsigned)yy1_ < 256u) && ((unsigned)xx1_ < 256u);
  const unsigned short* p0 = ycl + ((size_t)b * 65536 + (size_t)yy0_ * 256 + xx0_) * 32;
  const unsigned short* p1 = ycl + ((size_t)b * 65536 + (size_t)yy1_ * 256 + xx1_) * 32;
  s16x8 v0[4], v1[4];
#pragma unroll
  for (int h = 0; h < 4; ++h) v0[h] = in0 ? *(const s16x8*)&p0[h * 8] : z8;
#pragma unroll
  for (int h = 0; h < 4; ++h) v1[h] = in1 ? *(const s16x8*)&p1[h * 8] : z8;

  for (int i = tid; i < 1728; i += 256) {
    int row = i / 96, rem = i - row * 96, xc = rem >> 5, c = rem & 31;
    int yy = y0 + row;
    float uy = ((float)yy + 0.5f) * (1.f / 16.f) - 0.5f;
    float fy = floorf(uy);
    float ty = uy - fy;
    int iy0 = (int)fy;
    int iy0c = max(0, iy0), iy1c = min(15, iy0 + 1);
    int gxx = min(15, max(0, gx - 1 + xc));
    const float* base = lnf + (size_t)b * 8192 + c * 256;
    float a0 = base[iy0c * 16 + gxx], a1 = base[iy1c * 16 + gxx];
    vvb[i] = f2bf(a0 + ty * (a1 - a0));
  }

  {
    int sw0 = (i0 & 3) ^ ((i0 >> 2) & 3);
    int sw1 = (i1 & 3) ^ ((i1 >> 2) & 3);
#pragma unroll
    for (int h = 0; h < 4; ++h) {
      float f0[8], f1[8];
#pragma unroll
      for (int j = 0; j < 8; ++j) {
        float sc = mrs[b * 32 + h * 8 + j];
        float sh = mrs[512 + b * 32 + h * 8 + j];
        float a = bf2f((unsigned short)v0[h][j]) * sc + sh;
        f0[j] = a * sigmoidf_(a);
        float c = bf2f((unsigned short)v1[h][j]) * sc + sh;
        f1[j] = c * sigmoidf_(c);
      }
      *(s16x8*)&comb[i0 * 32 + (((h ^ sw0) & 3) << 3)] = pk8(f0);
      if (i1 < 324) *(s16x8*)&comb[i1 * 32 + (((h ^ sw1) & 3) << 3)] = pk8(f1);
    }
  }
  __syncthreads();  // barrier 1: comb(conv) + vvb ready

  // ---- phase A MFMA: ic 0..31 ----
  f32x4 acc[4][2];
  float b0 = gate_b[lr], b1 = gate_b[16 + lr];
#pragma unroll
  for (int mi = 0; mi < 4; ++mi) {
    acc[mi][0] = (f32x4){b0, b0, b0, b0};
    acc[mi][1] = (f32x4){b1, b1, b1, b1};
  }
#pragma unroll
  for (int ky = 0; ky < 3; ++ky)
#pragma unroll
    for (int kx = 0; kx < 3; ++kx) {
      int tap = ky * 3 + kx;
      const unsigned short* wb = wgb + tap * 2048;
      s16x8 bf00 = *(const s16x8*)&wb[lr * 64 + lg * 8];
      s16x8 bf10 = *(const s16x8*)&wb[(16 + lr) * 64 + lg * 8];
#pragma unroll
      for (int mi = 0; mi < 4; ++mi) {
        int s = (wv * 4 + mi + ky) * 18 + lr + kx;
        s16x8 a = *(const s16x8*)&comb[s * 32 + ((lg ^ (s & 3) ^ ((s >> 2) & 3)) << 3)];
        acc[mi][0] = __builtin_amdgcn_mfma_f32_16x16x32_bf16(a, bf00, acc[mi][0], 0, 0, 0);
        acc[mi][1] = __builtin_amdgcn_mfma_f32_16x16x32_bf16(a, bf10, acc[mi][1], 0, 0, 0);
      }
    }

  // save cf centers (32 bf16) packed into 16 u32 regs before comb is overwritten
  unsigned cfp[4][2][2];
#pragma unroll
  for (int mi = 0; mi < 4; ++mi) {
    int m = wv * 4 + mi;
#pragma unroll
    for (int nt = 0; nt < 2; ++nt) {
      int oct = nt * 2 + (lr >> 3), el = lr & 7;
#pragma unroll
      for (int rh = 0; rh < 2; ++rh) {
        int px0 = lg * 4 + rh * 2, px1 = px0 + 1;
        int s0 = (m + 1) * 18 + px0 + 1, s1 = (m + 1) * 18 + px1 + 1;
        unsigned lo = comb[s0 * 32 + ((oct ^ (s0 & 3) ^ ((s0 >> 2) & 3)) << 3) + el];
        unsigned hi = comb[s1 * 32 + ((oct ^ (s1 & 3) ^ ((s1 >> 2) & 3)) << 3) + el];
        cfp[mi][nt][rh] = lo | (hi << 16);
      }
    }
  }
  __syncthreads();  // barrier 2: all reads of conv half done

  // ---- phase B staging: gcn half (horizontal interp from vvb) ----
  for (int i = tid; i < 324; i += 256) {
    int row = i / 18, col = i - row * 18;
    int yy = y0 + row, xx = x0 + col;
    int swa = (i & 3) ^ ((i >> 2) & 3);
    if (((unsigned)yy < 256u) && ((unsigned)xx < 256u)) {
      float ux = ((float)xx + 0.5f) * (1.f / 16.f) - 0.5f;
      float fx = floorf(ux);
      float tx = ux - fx;
      int dx0 = (int)fx - (gx - 1);   // in {0,1}
      const unsigned short* va = &vvb[(row * 3 + dx0) * 32];
      const unsigned short* vb = va + 32;
#pragma unroll
      for (int h = 0; h < 4; ++h) {
        s16x8 av = *(const s16x8*)&va[h * 8];
        s16x8 bv = *(const s16x8*)&vb[h * 8];
        float f[8];
#pragma unroll
        for (int j = 0; j < 8; ++j) {
          float a = bf2f((unsigned short)av[j]);
          f[j] = a + tx * (bf2f((unsigned short)bv[j]) - a);
        }
        *(s16x8*)&comb[i * 32 + (((h ^ swa) & 3) << 3)] = pk8(f);
      }
    } else {
#pragma unroll
      for (int h = 0; h < 4; ++h) *(s16x8*)&comb[i * 32 + (((h ^ swa) & 3) << 3)] = z8;
    }
  }
  __syncthreads();  // barrier 3: comb(gcn) ready

  // ---- phase B MFMA: ic 32..63 ----
#pragma unroll
  for (int ky = 0; ky < 3; ++ky)
#pragma unroll
    for (int kx = 0; kx < 3; ++kx) {
      int tap = ky * 3 + kx;
      const unsigned short* wb = wgb + tap * 2048;
      s16x8 bf01 = *(const s16x8*)&wb[lr * 64 + 32 + lg * 8];
      s16x8 bf11 = *(const s16x8*)&wb[(16 + lr) * 64 + 32 + lg * 8];
#pragma unroll
      for (int mi = 0; mi < 4; ++mi) {
        int s = (wv * 4 + mi + ky) * 18 + lr + kx;
        s16x8 a = *(const s16x8*)&comb[s * 32 + ((lg ^ (s & 3) ^ ((s >> 2) & 3)) << 3)];
        acc[mi][0] = __builtin_amdgcn_mfma_f32_16x16x32_bf16(a, bf01, acc[mi][0], 0, 0, 0);
        acc[mi][1] = __builtin_amdgcn_mfma_f32_16x16x32_bf16(a, bf11, acc[mi][1], 0, 0, 0);
      }
    }

  // ---- epilogue: gate, merge (cf from regs, gu from live LDS), FiLM, store ----
#pragma unroll
  for (int mi = 0; mi < 4; ++mi) {
    int m = wv * 4 + mi;
#pragma unroll
    for (int nt = 0; nt < 2; ++nt) {
      int o = nt * 16 + lr;
      int oct = nt * 2 + (lr >> 3), el = lr & 7;
      f32x4 a = acc[mi][nt];
      float gamma = tpv[b * 64 + o] + 1.0f, beta = tpv[b * 64 + 32 + o];
      f32x4 res;
#pragma unroll
      for (int rr = 0; rr < 4; ++rr) {
        int px = lg * 4 + rr;
        int s = (m + 1) * 18 + px + 1;
        unsigned cfu = cfp[mi][nt][rr >> 1];
        float cf = bf2f((unsigned short)((rr & 1) ? (cfu >> 16) : (cfu & 0xffff)));
        float gu = bf2f(comb[s * 32 + ((oct ^ (s & 3) ^ ((s >> 2) & 3)) << 3) + el]);
        float gate = sigmoidf_(a[rr]);
        float merged = gate * cf + (1.f - gate) * gu;
        res[rr] = merged * gamma + beta;
      }
      *(f32x4*)&out[((size_t)(b * 32 + o)) * 65536 + (size_t)(gy * 16 + m) * 256 + gx * 16 + lg * 4] = res;
    }
  }
}

extern "C" void kernel_launch(void* const* d_in, const int* in_sizes, int n_in,
                              void* d_out, int out_size, void* d_ws, size_t ws_size,
                              hipStream_t stream) {
  const float* x      = (const float*)d_in[0];
  const float* t      = (const float*)d_in[1];
  const float* conv_w = (const float*)d_in[2];
  const float* conv_b = (const float*)d_in[3];
  const float* gn_g   = (const float*)d_in[4];
  const float* gn_b   = (const float*)d_in[5];
  const float* gcn_w  = (const float*)d_in[6];
  const float* gcn_b  = (const float*)d_in[7];
  const float* ln_g   = (const float*)d_in[8];
  const float* ln_b   = (const float*)d_in[9];
  const float* gate_w = (const float*)d_in[10];
  const float* gate_b = (const float*)d_in[11];
  const float* tp_w   = (const float*)d_in[12];
  const float* tp_b   = (const float*)d_in[13];

  float* ws = (float*)d_ws;
  unsigned short* ycl = (unsigned short*)ws;        // 33,554,432 u16 (channel-last y)
  float* st    = ws + 16777216;                     // 256
  float* mrs   = st + 256;                          // 1024
  float* nodes = mrs + 1024;                        // 139,264
  float* lnf   = nodes + 139264;                    // 131,072
  float* tpv   = lnf + 131072;                      // 1,024
  unsigned short* wcb = (unsigned short*)(tpv + 1024);   // 9,216 u16
  unsigned short* wgb = wcb + 9216;                 // 18,432 u16

  hipMemsetAsync(st, 0, 256 * sizeof(float), stream);
  prep_misc<<<76, 256, 0, stream>>>(conv_w, gate_w, t, tp_w, tp_b, wcb, wgb, tpv);
  conv1_mfma<<<4096, 256, 0, stream>>>(x, wcb, conv_b, ycl, st, nodes);
  gn_finalize<<<1, 512, 0, stream>>>(st, gn_g, gn_b, mrs);
  gcn_fused<<<2048, 64, 0, stream>>>(nodes, gcn_w, gcn_b, ln_g, ln_b, lnf);
  fused_gate_mfma<<<4096, 256, 0, stream>>>(ycl, mrs, lnf, wgb, gate_b, tpv,
                                            (float*)d_out);
}

// Round 12
// 244.011 us; speedup vs baseline: 1.1453x; 1.1453x over previous
//
#include <hip/hip_runtime.h>
#include <hip/hip_bf16.h>
#include <math.h>

typedef __attribute__((ext_vector_type(4))) float f32x4;
typedef __attribute__((ext_vector_type(8))) short s16x8;
typedef __attribute__((ext_vector_type(4))) short s16x4;

static __device__ __forceinline__ float sigmoidf_(float v) { return 1.0f / (1.0f + __expf(-v)); }
static __device__ __forceinline__ unsigned short f2bf(float f) {
  unsigned u = __float_as_uint(f);
  u += 0x7fffu + ((u >> 16) & 1u);
  return (unsigned short)(u >> 16);
}
static __device__ __forceinline__ float bf2f(unsigned short h) {
  return __uint_as_float(((unsigned)h) << 16);
}
static __device__ __forceinline__ s16x4 pk4(float a, float b, float c, float d) {
  union { __hip_bfloat162 h2[2]; s16x4 v; } u;
  u.h2[0] = __float22bfloat162_rn(make_float2(a, b));
  u.h2[1] = __float22bfloat162_rn(make_float2(c, d));
  return u.v;
}
static __device__ __forceinline__ s16x8 pk8(const float* f) {
  union { __hip_bfloat162 h2[4]; s16x8 v; } u;
  u.h2[0] = __float22bfloat162_rn(make_float2(f[0], f[1]));
  u.h2[1] = __float22bfloat162_rn(make_float2(f[2], f[3]));
  u.h2[2] = __float22bfloat162_rn(make_float2(f[4], f[5]));
  u.h2[3] = __float22bfloat162_rn(make_float2(f[6], f[7]));
  return u.v;
}

// K0: weight fragments in LANE ORDER + tproj.
// wcF[tap][f][lane][8]: conv weights, frag f: o=f*16+(lane&15), c=(lane>>4)*8+j
// wgF[p][tap][f][lane][8]: gate weights, phase p: ic=p*32+(lane>>4)*8+j
__global__ __launch_bounds__(256) void prep_misc(const float* __restrict__ cw,
                                                 const float* __restrict__ gw,
                                                 const float* __restrict__ t,
                                                 const float* __restrict__ tw,
                                                 const float* __restrict__ tb,
                                                 unsigned short* __restrict__ wcF,
                                                 unsigned short* __restrict__ wgF,
                                                 float* __restrict__ tpo) {
  int blk = blockIdx.x;
  if (blk < 72) {
    int i = blk * 256 + threadIdx.x;
    if (i < 9216) {
      int j = i & 7, lane = (i >> 3) & 63, f = (i >> 9) & 1, tap = i >> 10;
      int o = f * 16 + (lane & 15), c = (lane >> 4) * 8 + j;
      wcF[i] = f2bf(cw[(o * 32 + c) * 9 + tap]);
    }
    if (i < 18432) {
      int j = i & 7, lane = (i >> 3) & 63, f = (i >> 9) & 1;
      int rem = i >> 10;               // 0..17
      int tap = rem % 9, p = rem / 9;
      int o = f * 16 + (lane & 15), ic = p * 32 + (lane >> 4) * 8 + j;
      wgF[i] = f2bf(gw[(o * 64 + ic) * 9 + tap]);
    }
  } else {
    int idx = (blk - 72) * 256 + threadIdx.x;  // < 1024
    int b = idx >> 6, j = idx & 63;
    const float* tr = t + b * 256;
    const float* wr = tw + j * 256;
    float s = tb[j];
    for (int k = 0; k < 256; ++k) s = fmaf(tr[k], wr[k], s);
    tpo[idx] = s;
  }
}

// K1: conv3x3 MFMA; weights LDS-resident (lane-indexed, conflict-free reads).
__global__ __launch_bounds__(256) void conv1_mfma(const float* __restrict__ x,
                                                  const unsigned short* __restrict__ wcF,
                                                  const float* __restrict__ conv_b,
                                                  unsigned short* __restrict__ ycl,
                                                  float* __restrict__ stats,
                                                  float* __restrict__ nodes) {
  __shared__ alignas(16) unsigned short xt[324 * 32];   // 20.7KB
  __shared__ alignas(16) unsigned short wl[9216];       // 18KB weight fragments
  __shared__ float gpart[8][2][4];
  int blk = blockIdx.x;
  int b = blk >> 8, r = blk & 255, gy = r >> 4, gx = r & 15;
  int tid = threadIdx.x;
  int y0 = gy * 16 - 1, x0 = gx * 16 - 1;
  for (int i = tid; i < 1152; i += 256)
    *(s16x8*)&wl[i * 8] = *(const s16x8*)&wcF[i * 8];
  for (int i = tid; i < 2592; i += 256) {
    int q = i / 324, s = i - q * 324;
    int row = s / 18, col = s - row * 18;
    int yy = y0 + row, xx = x0 + col;
    float v0 = 0, v1 = 0, v2 = 0, v3 = 0;
    if ((unsigned)yy < 256u && (unsigned)xx < 256u) {
      const float* p = x + ((size_t)(b * 32 + q * 4)) * 65536 + yy * 256 + xx;
      v0 = p[0]; v1 = p[65536]; v2 = p[131072]; v3 = p[196608];
    }
    int slot = (q >> 1) ^ (s & 3) ^ ((s >> 2) & 3);
    int off = s * 32 + slot * 8 + (q & 1) * 4;
    *(s16x4*)&xt[off] = pk4(v0, v1, v2, v3);
  }
  __syncthreads();

  int wv = tid >> 6, lane = tid & 63;
  int lr = lane & 15, lg = lane >> 4;

  // fused patch means
#pragma unroll
  for (int cc = 0; cc < 8; ++cc) {
    int c = wv * 8 + cc;
    int q = c >> 2, jj = c & 3;
    float s = 0.f;
#pragma unroll
    for (int pp = 0; pp < 4; ++pp) {
      int p = lane * 4 + pp;
      int sp = ((p >> 4) + 1) * 18 + (p & 15) + 1;
      int off = sp * 32 + (((q >> 1) ^ (sp & 3) ^ ((sp >> 2) & 3)) << 3) + (q & 1) * 4 + jj;
      s += bf2f(xt[off]);
    }
    for (int m = 1; m < 64; m <<= 1) s += __shfl_xor(s, m);
    if (lane == 0) nodes[(size_t)blk * 34 + c] = s * (1.f / 256.f);
  }
  if (tid == 0) {
    nodes[(size_t)blk * 34 + 32] = (float)gy * (1.f / 16.f);
    nodes[(size_t)blk * 34 + 33] = (float)gx * (1.f / 16.f);
  }

  // MFMA: A=weights (LDS), B=pixels. D row(lg*4+rr)=o, col(lr)=px.
  f32x4 acc[4][2];
  f32x4 cb0 = *(const f32x4*)&conv_b[lg * 4];
  f32x4 cb1 = *(const f32x4*)&conv_b[16 + lg * 4];
#pragma unroll
  for (int mi = 0; mi < 4; ++mi) { acc[mi][0] = cb0; acc[mi][1] = cb1; }
#pragma unroll
  for (int tap = 0; tap < 9; ++tap) {
    s16x8 wf0 = *(const s16x8*)&wl[tap * 1024 + lane * 8];
    s16x8 wf1 = *(const s16x8*)&wl[tap * 1024 + 512 + lane * 8];
    int ky = tap / 3, kx = tap - ky * 3;
#pragma unroll
    for (int mi = 0; mi < 4; ++mi) {
      int s = (wv * 4 + mi + ky) * 18 + lr + kx;
      int offB = s * 32 + ((lg ^ (s & 3) ^ ((s >> 2) & 3)) << 3);
      s16x8 xf = *(const s16x8*)&xt[offB];
      acc[mi][0] = __builtin_amdgcn_mfma_f32_16x16x32_bf16(wf0, xf, acc[mi][0], 0, 0, 0);
      acc[mi][1] = __builtin_amdgcn_mfma_f32_16x16x32_bf16(wf1, xf, acc[mi][1], 0, 0, 0);
    }
  }
  // epilogue: channel-last store
#pragma unroll
  for (int mi = 0; mi < 4; ++mi) {
    int oy = gy * 16 + wv * 4 + mi;
    size_t pixbase = ((size_t)b * 65536 + (size_t)oy * 256 + gx * 16 + lr) * 32;
#pragma unroll
    for (int nt = 0; nt < 2; ++nt) {
      f32x4 a = acc[mi][nt];
      *(s16x4*)&ycl[pixbase + nt * 16 + lg * 4] = pk4(a[0], a[1], a[2], a[3]);
    }
  }
  // fused GN stats
#pragma unroll
  for (int nt = 0; nt < 2; ++nt) {
    float s = 0.f, q = 0.f;
#pragma unroll
    for (int mi = 0; mi < 4; ++mi)
#pragma unroll
      for (int rr = 0; rr < 4; ++rr) {
        float v = acc[mi][nt][rr];
        s += v; q += v * v;
      }
    for (int m = 1; m < 16; m <<= 1) { s += __shfl_xor(s, m); q += __shfl_xor(q, m); }
    if (lr == 0) { gpart[nt * 4 + lg][0][wv] = s; gpart[nt * 4 + lg][1][wv] = q; }
  }
  __syncthreads();
  if (tid < 16) {
    int g = tid >> 1, which = tid & 1;
    float v = gpart[g][which][0] + gpart[g][which][1] + gpart[g][which][2] + gpart[g][which][3];
    atomicAdd(&stats[(which ? 128 : 0) + b * 8 + g], v);
  }
}

// K2: fold GN into per-(b,c) scale/shift
__global__ void gn_finalize(const float* __restrict__ stats,
                            const float* __restrict__ gn_g,
                            const float* __restrict__ gn_b,
                            float* __restrict__ mrs) {
  int i = threadIdx.x;  // 512
  int b = i >> 5, c = i & 31, g = c >> 2;
  float s = stats[b * 8 + g], q = stats[128 + b * 8 + g];
  const float n = 262144.f;
  float mean = s / n;
  float var = q / n - mean * mean;
  float rs = rsqrtf(var + 1e-5f);
  float scale = rs * gn_g[c];
  mrs[i] = scale;
  mrs[512 + i] = gn_b[c] - mean * scale;
}

__device__ __forceinline__ float dinv_at(int gy, int gx) {
  return rsqrtf((float)(1 + (gy > 0) + (gy < 15) + (gx > 0) + (gx < 15)));
}

// K3: fused GCN
__global__ __launch_bounds__(64) void gcn_fused(const float* __restrict__ nodes,
                                                const float* __restrict__ gw,
                                                const float* __restrict__ gcn_b,
                                                const float* __restrict__ ln_g,
                                                const float* __restrict__ ln_b,
                                                float* __restrict__ lnout) {
  int n = blockIdx.x * 2 + (threadIdx.x >> 5);
  int o = threadIdx.x & 31;
  int r = n & 255, gy = r >> 4, gx = r & 15;
  float dn = dinv_at(gy, gx);
  float s = 0.f;
  {
    const float* nr = nodes + (size_t)n * 34;
    float hh = 0.f;
#pragma unroll
    for (int k = 0; k < 34; ++k) hh = fmaf(nr[k], gw[k * 32 + o], hh);
    s = hh * dn;
  }
  if (gy > 0) {
    const float* nr = nodes + (size_t)(n - 16) * 34;
    float hh = 0.f;
#pragma unroll
    for (int k = 0; k < 34; ++k) hh = fmaf(nr[k], gw[k * 32 + o], hh);
    s += hh * dinv_at(gy - 1, gx);
  }
  if (gy < 15) {
    const float* nr = nodes + (size_t)(n + 16) * 34;
    float hh = 0.f;
#pragma unroll
    for (int k = 0; k < 34; ++k) hh = fmaf(nr[k], gw[k * 32 + o], hh);
    s += hh * dinv_at(gy + 1, gx);
  }
  if (gx > 0) {
    const float* nr = nodes + (size_t)(n - 1) * 34;
    float hh = 0.f;
#pragma unroll
    for (int k = 0; k < 34; ++k) hh = fmaf(nr[k], gw[k * 32 + o], hh);
    s += hh * dinv_at(gy, gx - 1);
  }
  if (gx < 15) {
    const float* nr = nodes + (size_t)(n + 1) * 34;
    float hh = 0.f;
#pragma unroll
    for (int k = 0; k < 34; ++k) hh = fmaf(nr[k], gw[k * 32 + o], hh);
    s += hh * dinv_at(gy, gx + 1);
  }
  float g = dn * s + gcn_b[o];
  float mu = g;
  for (int m = 16; m; m >>= 1) mu += __shfl_xor(mu, m);
  mu *= (1.0f / 32.0f);
  float d = g - mu;
  float v = d * d;
  for (int m = 16; m; m >>= 1) v += __shfl_xor(v, m);
  v *= (1.0f / 32.0f);
  lnout[n * 32 + o] = d * rsqrtf(v + 1e-5f) * ln_g[o] + ln_b[o];
}

// K6: k-split 2-phase gate conv; weights LDS-resident per phase (lane-indexed).
__global__ __launch_bounds__(256) void fused_gate_mfma(
    const unsigned short* __restrict__ ycl, const float* __restrict__ mrs,
    const float* __restrict__ lnf, const unsigned short* __restrict__ wgF,
    const float* __restrict__ gate_b, const float* __restrict__ tpv,
    float* __restrict__ out) {
  __shared__ alignas(16) unsigned short comb[324 * 32];   // 20.7KB
  __shared__ alignas(16) unsigned short vvb[18 * 3 * 32]; // 3.4KB
  __shared__ alignas(16) unsigned short wl[9216];         // 18KB per-phase weights
  int blk = blockIdx.x;
  int b = blk >> 8, r = blk & 255, gy = r >> 4, gx = r & 15;
  int tid = threadIdx.x;
  int wv = tid >> 6, lane = tid & 63;
  int lr = lane & 15, lg = lane >> 4;
  int y0 = gy * 16 - 1, x0 = gx * 16 - 1;
  const s16x8 z8 = (s16x8){0, 0, 0, 0, 0, 0, 0, 0};

  // ---- phase A staging: weights(p0) + conv half + vvb ----
  for (int i = tid; i < 1152; i += 256)
    *(s16x8*)&wl[i * 8] = *(const s16x8*)&wgF[i * 8];

  int i0 = tid, i1 = tid + 256;
  int row0 = i0 / 18, col0 = i0 - row0 * 18;
  int yy0_ = y0 + row0, xx0_ = x0 + col0;
  bool in0 = ((unsigned)yy0_ < 256u) && ((unsigned)xx0_ < 256u);
  int row1 = i1 / 18, col1 = i1 - row1 * 18;
  int yy1_ = y0 + row1, xx1_ = x0 + col1;
  bool in1 = (i1 < 324) && ((unsigned)yy1_ < 256u) && ((unsigned)xx1_ < 256u);
  const unsigned short* p0 = ycl + ((size_t)b * 65536 + (size_t)yy0_ * 256 + xx0_) * 32;
  const unsigned short* p1 = ycl + ((size_t)b * 65536 + (size_t)yy1_ * 256 + xx1_) * 32;
  s16x8 v0[4], v1[4];
#pragma unroll
  for (int h = 0; h < 4; ++h) v0[h] = in0 ? *(const s16x8*)&p0[h * 8] : z8;
#pragma unroll
  for (int h = 0; h < 4; ++h) v1[h] = in1 ? *(const s16x8*)&p1[h * 8] : z8;

  for (int i = tid; i < 1728; i += 256) {
    int row = i / 96, rem = i - row * 96, xc = rem >> 5, c = rem & 31;
    int yy = y0 + row;
    float uy = ((float)yy + 0.5f) * (1.f / 16.f) - 0.5f;
    float fy = floorf(uy);
    float ty = uy - fy;
    int iy0 = (int)fy;
    int iy0c = max(0, iy0), iy1c = min(15, iy0 + 1);
    int gxx = min(15, max(0, gx - 1 + xc));
    const float* base = lnf + (size_t)b * 8192 + c * 256;
    float a0 = base[iy0c * 16 + gxx], a1 = base[iy1c * 16 + gxx];
    vvb[i] = f2bf(a0 + ty * (a1 - a0));
  }

  {
    int sw0 = (i0 & 3) ^ ((i0 >> 2) & 3);
    int sw1 = (i1 & 3) ^ ((i1 >> 2) & 3);
#pragma unroll
    for (int h = 0; h < 4; ++h) {
      float f0[8], f1[8];
#pragma unroll
      for (int j = 0; j < 8; ++j) {
        float sc = mrs[b * 32 + h * 8 + j];
        float sh = mrs[512 + b * 32 + h * 8 + j];
        float a = bf2f((unsigned short)v0[h][j]) * sc + sh;
        f0[j] = a * sigmoidf_(a);
        float c = bf2f((unsigned short)v1[h][j]) * sc + sh;
        f1[j] = c * sigmoidf_(c);
      }
      *(s16x8*)&comb[i0 * 32 + (((h ^ sw0) & 3) << 3)] = pk8(f0);
      if (i1 < 324) *(s16x8*)&comb[i1 * 32 + (((h ^ sw1) & 3) << 3)] = pk8(f1);
    }
  }
  __syncthreads();  // barrier 1

  // ---- phase A MFMA: ic 0..31, weights from LDS ----
  f32x4 acc[4][2];
  float b0 = gate_b[lr], b1 = gate_b[16 + lr];
#pragma unroll
  for (int mi = 0; mi < 4; ++mi) {
    acc[mi][0] = (f32x4){b0, b0, b0, b0};
    acc[mi][1] = (f32x4){b1, b1, b1, b1};
  }
#pragma unroll
  for (int tap = 0; tap < 9; ++tap) {
    s16x8 wlo = *(const s16x8*)&wl[tap * 1024 + lane * 8];
    s16x8 whi = *(const s16x8*)&wl[tap * 1024 + 512 + lane * 8];
    int ky = tap / 3, kx = tap - ky * 3;
#pragma unroll
    for (int mi = 0; mi < 4; ++mi) {
      int s = (wv * 4 + mi + ky) * 18 + lr + kx;
      s16x8 a = *(const s16x8*)&comb[s * 32 + ((lg ^ (s & 3) ^ ((s >> 2) & 3)) << 3)];
      acc[mi][0] = __builtin_amdgcn_mfma_f32_16x16x32_bf16(a, wlo, acc[mi][0], 0, 0, 0);
      acc[mi][1] = __builtin_amdgcn_mfma_f32_16x16x32_bf16(a, whi, acc[mi][1], 0, 0, 0);
    }
  }

  // save cf centers before comb is overwritten
  unsigned cfp[4][2][2];
#pragma unroll
  for (int mi = 0; mi < 4; ++mi) {
    int m = wv * 4 + mi;
#pragma unroll
    for (int nt = 0; nt < 2; ++nt) {
      int oct = nt * 2 + (lr >> 3), el = lr & 7;
#pragma unroll
      for (int rh = 0; rh < 2; ++rh) {
        int px0 = lg * 4 + rh * 2, px1 = px0 + 1;
        int s0 = (m + 1) * 18 + px0 + 1, s1 = (m + 1) * 18 + px1 + 1;
        unsigned lo = comb[s0 * 32 + ((oct ^ (s0 & 3) ^ ((s0 >> 2) & 3)) << 3) + el];
        unsigned hi = comb[s1 * 32 + ((oct ^ (s1 & 3) ^ ((s1 >> 2) & 3)) << 3) + el];
        cfp[mi][nt][rh] = lo | (hi << 16);
      }
    }
  }
  __syncthreads();  // barrier 2: phase-A reads done (comb + wl reusable)

  // ---- phase B staging: weights(p1) + gcn half ----
  for (int i = tid; i < 1152; i += 256)
    *(s16x8*)&wl[i * 8] = *(const s16x8*)&wgF[9216 + i * 8];

  for (int i = tid; i < 324; i += 256) {
    int row = i / 18, col = i - row * 18;
    int yy = y0 + row, xx = x0 + col;
    int swa = (i & 3) ^ ((i >> 2) & 3);
    if (((unsigned)yy < 256u) && ((unsigned)xx < 256u)) {
      float ux = ((float)xx + 0.5f) * (1.f / 16.f) - 0.5f;
      float fx = floorf(ux);
      float tx = ux - fx;
      int dx0 = (int)fx - (gx - 1);   // in {0,1}
      const unsigned short* va = &vvb[(row * 3 + dx0) * 32];
      const unsigned short* vb = va + 32;
#pragma unroll
      for (int h = 0; h < 4; ++h) {
        s16x8 av = *(const s16x8*)&va[h * 8];
        s16x8 bv = *(const s16x8*)&vb[h * 8];
        float f[8];
#pragma unroll
        for (int j = 0; j < 8; ++j) {
          float a = bf2f((unsigned short)av[j]);
          f[j] = a + tx * (bf2f((unsigned short)bv[j]) - a);
        }
        *(s16x8*)&comb[i * 32 + (((h ^ swa) & 3) << 3)] = pk8(f);
      }
    } else {
#pragma unroll
      for (int h = 0; h < 4; ++h) *(s16x8*)&comb[i * 32 + (((h ^ swa) & 3) << 3)] = z8;
    }
  }
  __syncthreads();  // barrier 3

  // ---- phase B MFMA: ic 32..63 ----
#pragma unroll
  for (int tap = 0; tap < 9; ++tap) {
    s16x8 wlo = *(const s16x8*)&wl[tap * 1024 + lane * 8];
    s16x8 whi = *(const s16x8*)&wl[tap * 1024 + 512 + lane * 8];
    int ky = tap / 3, kx = tap - ky * 3;
#pragma unroll
    for (int mi = 0; mi < 4; ++mi) {
      int s = (wv * 4 + mi + ky) * 18 + lr + kx;
      s16x8 a = *(const s16x8*)&comb[s * 32 + ((lg ^ (s & 3) ^ ((s >> 2) & 3)) << 3)];
      acc[mi][0] = __builtin_amdgcn_mfma_f32_16x16x32_bf16(a, wlo, acc[mi][0], 0, 0, 0);
      acc[mi][1] = __builtin_amdgcn_mfma_f32_16x16x32_bf16(a, whi, acc[mi][1], 0, 0, 0);
    }
  }

  // ---- epilogue ----
#pragma unroll
  for (int mi = 0; mi < 4; ++mi) {
    int m = wv * 4 + mi;
#pragma unroll
    for (int nt = 0; nt < 2; ++nt) {
      int o = nt * 16 + lr;
      int oct = nt * 2 + (lr >> 3), el = lr & 7;
      f32x4 a = acc[mi][nt];
      float gamma = tpv[b * 64 + o] + 1.0f, beta = tpv[b * 64 + 32 + o];
      f32x4 res;
#pragma unroll
      for (int rr = 0; rr < 4; ++rr) {
        int px = lg * 4 + rr;
        int s = (m + 1) * 18 + px + 1;
        unsigned cfu = cfp[mi][nt][rr >> 1];
        float cf = bf2f((unsigned short)((rr & 1) ? (cfu >> 16) : (cfu & 0xffff)));
        float gu = bf2f(comb[s * 32 + ((oct ^ (s & 3) ^ ((s >> 2) & 3)) << 3) + el]);
        float gate = sigmoidf_(a[rr]);
        float merged = gate * cf + (1.f - gate) * gu;
        res[rr] = merged * gamma + beta;
      }
      *(f32x4*)&out[((size_t)(b * 32 + o)) * 65536 + (size_t)(gy * 16 + m) * 256 + gx * 16 + lg * 4] = res;
    }
  }
}

extern "C" void kernel_launch(void* const* d_in, const int* in_sizes, int n_in,
                              void* d_out, int out_size, void* d_ws, size_t ws_size,
                              hipStream_t stream) {
  const float* x      = (const float*)d_in[0];
  const float* t      = (const float*)d_in[1];
  const float* conv_w = (const float*)d_in[2];
  const float* conv_b = (const float*)d_in[3];
  const float* gn_g   = (const float*)d_in[4];
  const float* gn_b   = (const float*)d_in[5];
  const float* gcn_w  = (const float*)d_in[6];
  const float* gcn_b  = (const float*)d_in[7];
  const float* ln_g   = (const float*)d_in[8];
  const float* ln_b   = (const float*)d_in[9];
  const float* gate_w = (const float*)d_in[10];
  const float* gate_b = (const float*)d_in[11];
  const float* tp_w   = (const float*)d_in[12];
  const float* tp_b   = (const float*)d_in[13];

  float* ws = (float*)d_ws;
  unsigned short* ycl = (unsigned short*)ws;        // 33,554,432 u16
  float* st    = ws + 16777216;                     // 256
  float* mrs   = st + 256;                          // 1024
  float* nodes = mrs + 1024;                        // 139,264
  float* lnf   = nodes + 139264;                    // 131,072
  float* tpv   = lnf + 131072;                      // 1,024
  unsigned short* wcF = (unsigned short*)(tpv + 1024);   // 9,216 u16
  unsigned short* wgF = wcF + 9216;                 // 18,432 u16

  hipMemsetAsync(st, 0, 256 * sizeof(float), stream);
  prep_misc<<<76, 256, 0, stream>>>(conv_w, gate_w, t, tp_w, tp_b, wcF, wgF, tpv);
  conv1_mfma<<<4096, 256, 0, stream>>>(x, wcF, conv_b, ycl, st, nodes);
  gn_finalize<<<1, 512, 0, stream>>>(st, gn_g, gn_b, mrs);
  gcn_fused<<<2048, 64, 0, stream>>>(nodes, gcn_w, gcn_b, ln_g, ln_b, lnf);
  fused_gate_mfma<<<4096, 256, 0, stream>>>(ycl, mrs, lnf, wgF, gate_b, tpv,
                                            (float*)d_out);
}

// Round 13
// 211.588 us; speedup vs baseline: 1.3208x; 1.1532x over previous
//
#include <hip/hip_runtime.h>
#include <hip/hip_bf16.h>
#include <math.h>

typedef __attribute__((ext_vector_type(4))) float f32x4;
typedef __attribute__((ext_vector_type(8))) short s16x8;
typedef __attribute__((ext_vector_type(4))) short s16x4;

static __device__ __forceinline__ float sigmoidf_(float v) { return 1.0f / (1.0f + __expf(-v)); }
static __device__ __forceinline__ unsigned short f2bf(float f) {
  unsigned u = __float_as_uint(f);
  u += 0x7fffu + ((u >> 16) & 1u);
  return (unsigned short)(u >> 16);
}
static __device__ __forceinline__ float bf2f(unsigned short h) {
  return __uint_as_float(((unsigned)h) << 16);
}
static __device__ __forceinline__ s16x4 pk4(float a, float b, float c, float d) {
  union { __hip_bfloat162 h2[2]; s16x4 v; } u;
  u.h2[0] = __float22bfloat162_rn(make_float2(a, b));
  u.h2[1] = __float22bfloat162_rn(make_float2(c, d));
  return u.v;
}
static __device__ __forceinline__ s16x8 pk8(const float* f) {
  union { __hip_bfloat162 h2[4]; s16x8 v; } u;
  u.h2[0] = __float22bfloat162_rn(make_float2(f[0], f[1]));
  u.h2[1] = __float22bfloat162_rn(make_float2(f[2], f[3]));
  u.h2[2] = __float22bfloat162_rn(make_float2(f[4], f[5]));
  u.h2[3] = __float22bfloat162_rn(make_float2(f[6], f[7]));
  return u.v;
}
// XCD-aware swizzle: dispatch id -> logical block; 4096 blocks, 8 XCDs,
// id%8 = XCD (round-robin) -> each XCD gets a contiguous 512-block chunk
// (= 2 whole images) so halo lines are L2-local.
static __device__ __forceinline__ int xcd_swz(int id) {
  return (id & 7) * 512 + (id >> 3);
}

// K0: weight fragments in LANE ORDER + tproj.
__global__ __launch_bounds__(256) void prep_misc(const float* __restrict__ cw,
                                                 const float* __restrict__ gw,
                                                 const float* __restrict__ t,
                                                 const float* __restrict__ tw,
                                                 const float* __restrict__ tb,
                                                 unsigned short* __restrict__ wcF,
                                                 unsigned short* __restrict__ wgF,
                                                 float* __restrict__ tpo) {
  int blk = blockIdx.x;
  if (blk < 72) {
    int i = blk * 256 + threadIdx.x;
    if (i < 9216) {
      int j = i & 7, lane = (i >> 3) & 63, f = (i >> 9) & 1, tap = i >> 10;
      int o = f * 16 + (lane & 15), c = (lane >> 4) * 8 + j;
      wcF[i] = f2bf(cw[(o * 32 + c) * 9 + tap]);
    }
    if (i < 18432) {
      int j = i & 7, lane = (i >> 3) & 63, f = (i >> 9) & 1;
      int rem = i >> 10;               // 0..17
      int tap = rem % 9, p = rem / 9;
      int o = f * 16 + (lane & 15), ic = p * 32 + (lane >> 4) * 8 + j;
      wgF[i] = f2bf(gw[(o * 64 + ic) * 9 + tap]);
    }
  } else {
    int idx = (blk - 72) * 256 + threadIdx.x;  // < 1024
    int b = idx >> 6, j = idx & 63;
    const float* tr = t + b * 256;
    const float* wr = tw + j * 256;
    float s = tb[j];
    for (int k = 0; k < 256; ++k) s = fmaf(tr[k], wr[k], s);
    tpo[idx] = s;
  }
}

// K1: conv3x3 MFMA; weights LDS-resident; XCD-swizzled blocks; fixed patch-mean order.
__global__ __launch_bounds__(256) void conv1_mfma(const float* __restrict__ x,
                                                  const unsigned short* __restrict__ wcF,
                                                  const float* __restrict__ conv_b,
                                                  unsigned short* __restrict__ ycl,
                                                  float* __restrict__ stats,
                                                  float* __restrict__ nodes) {
  __shared__ alignas(16) unsigned short xt[324 * 32];   // 20.7KB
  __shared__ alignas(16) unsigned short wl[9216];       // 18KB weight fragments
  __shared__ float gpart[8][2][4];
  int blk = xcd_swz(blockIdx.x);
  int b = blk >> 8, r = blk & 255, gy = r >> 4, gx = r & 15;
  int tid = threadIdx.x;
  int y0 = gy * 16 - 1, x0 = gx * 16 - 1;
  for (int i = tid; i < 1152; i += 256)
    *(s16x8*)&wl[i * 8] = *(const s16x8*)&wcF[i * 8];
  for (int i = tid; i < 2592; i += 256) {
    int q = i / 324, s = i - q * 324;
    int row = s / 18, col = s - row * 18;
    int yy = y0 + row, xx = x0 + col;
    float v0 = 0, v1 = 0, v2 = 0, v3 = 0;
    if ((unsigned)yy < 256u && (unsigned)xx < 256u) {
      const float* p = x + ((size_t)(b * 32 + q * 4)) * 65536 + yy * 256 + xx;
      v0 = p[0]; v1 = p[65536]; v2 = p[131072]; v3 = p[196608];
    }
    int slot = (q >> 1) ^ (s & 3) ^ ((s >> 2) & 3);
    int off = s * 32 + slot * 8 + (q & 1) * 4;
    *(s16x4*)&xt[off] = pk4(v0, v1, v2, v3);
  }
  __syncthreads();

  int wv = tid >> 6, lane = tid & 63;
  int lr = lane & 15, lg = lane >> 4;

  // fused patch means — p = pp*64 + lane: consecutive lanes read consecutive s
  // -> swizzled banks spread over 8 banks (~2-way, free) instead of 32-way.
#pragma unroll
  for (int cc = 0; cc < 8; ++cc) {
    int c = wv * 8 + cc;
    int q = c >> 2, jj = c & 3;
    float s = 0.f;
#pragma unroll
    for (int pp = 0; pp < 4; ++pp) {
      int p = pp * 64 + lane;
      int sp = ((p >> 4) + 1) * 18 + (p & 15) + 1;
      int off = sp * 32 + (((q >> 1) ^ (sp & 3) ^ ((sp >> 2) & 3)) << 3) + (q & 1) * 4 + jj;
      s += bf2f(xt[off]);
    }
    for (int m = 1; m < 64; m <<= 1) s += __shfl_xor(s, m);
    if (lane == 0) nodes[(size_t)blk * 34 + c] = s * (1.f / 256.f);
  }
  if (tid == 0) {
    nodes[(size_t)blk * 34 + 32] = (float)gy * (1.f / 16.f);
    nodes[(size_t)blk * 34 + 33] = (float)gx * (1.f / 16.f);
  }

  // MFMA: A=weights (LDS), B=pixels. D row(lg*4+rr)=o, col(lr)=px.
  f32x4 acc[4][2];
  f32x4 cb0 = *(const f32x4*)&conv_b[lg * 4];
  f32x4 cb1 = *(const f32x4*)&conv_b[16 + lg * 4];
#pragma unroll
  for (int mi = 0; mi < 4; ++mi) { acc[mi][0] = cb0; acc[mi][1] = cb1; }
#pragma unroll
  for (int tap = 0; tap < 9; ++tap) {
    s16x8 wf0 = *(const s16x8*)&wl[tap * 1024 + lane * 8];
    s16x8 wf1 = *(const s16x8*)&wl[tap * 1024 + 512 + lane * 8];
    int ky = tap / 3, kx = tap - ky * 3;
#pragma unroll
    for (int mi = 0; mi < 4; ++mi) {
      int s = (wv * 4 + mi + ky) * 18 + lr + kx;
      int offB = s * 32 + ((lg ^ (s & 3) ^ ((s >> 2) & 3)) << 3);
      s16x8 xf = *(const s16x8*)&xt[offB];
      acc[mi][0] = __builtin_amdgcn_mfma_f32_16x16x32_bf16(wf0, xf, acc[mi][0], 0, 0, 0);
      acc[mi][1] = __builtin_amdgcn_mfma_f32_16x16x32_bf16(wf1, xf, acc[mi][1], 0, 0, 0);
    }
  }
  // epilogue: channel-last store
#pragma unroll
  for (int mi = 0; mi < 4; ++mi) {
    int oy = gy * 16 + wv * 4 + mi;
    size_t pixbase = ((size_t)b * 65536 + (size_t)oy * 256 + gx * 16 + lr) * 32;
#pragma unroll
    for (int nt = 0; nt < 2; ++nt) {
      f32x4 a = acc[mi][nt];
      *(s16x4*)&ycl[pixbase + nt * 16 + lg * 4] = pk4(a[0], a[1], a[2], a[3]);
    }
  }
  // fused GN stats
#pragma unroll
  for (int nt = 0; nt < 2; ++nt) {
    float s = 0.f, q = 0.f;
#pragma unroll
    for (int mi = 0; mi < 4; ++mi)
#pragma unroll
      for (int rr = 0; rr < 4; ++rr) {
        float v = acc[mi][nt][rr];
        s += v; q += v * v;
      }
    for (int m = 1; m < 16; m <<= 1) { s += __shfl_xor(s, m); q += __shfl_xor(q, m); }
    if (lr == 0) { gpart[nt * 4 + lg][0][wv] = s; gpart[nt * 4 + lg][1][wv] = q; }
  }
  __syncthreads();
  if (tid < 16) {
    int g = tid >> 1, which = tid & 1;
    float v = gpart[g][which][0] + gpart[g][which][1] + gpart[g][which][2] + gpart[g][which][3];
    atomicAdd(&stats[(which ? 128 : 0) + b * 8 + g], v);
  }
}

// K2: fold GN into per-(b,c) scale/shift
__global__ void gn_finalize(const float* __restrict__ stats,
                            const float* __restrict__ gn_g,
                            const float* __restrict__ gn_b,
                            float* __restrict__ mrs) {
  int i = threadIdx.x;  // 512
  int b = i >> 5, c = i & 31, g = c >> 2;
  float s = stats[b * 8 + g], q = stats[128 + b * 8 + g];
  const float n = 262144.f;
  float mean = s / n;
  float var = q / n - mean * mean;
  float rs = rsqrtf(var + 1e-5f);
  float scale = rs * gn_g[c];
  mrs[i] = scale;
  mrs[512 + i] = gn_b[c] - mean * scale;
}

__device__ __forceinline__ float dinv_at(int gy, int gx) {
  return rsqrtf((float)(1 + (gy > 0) + (gy < 15) + (gx > 0) + (gx < 15)));
}

// K3: fused GCN
__global__ __launch_bounds__(64) void gcn_fused(const float* __restrict__ nodes,
                                                const float* __restrict__ gw,
                                                const float* __restrict__ gcn_b,
                                                const float* __restrict__ ln_g,
                                                const float* __restrict__ ln_b,
                                                float* __restrict__ lnout) {
  int n = blockIdx.x * 2 + (threadIdx.x >> 5);
  int o = threadIdx.x & 31;
  int r = n & 255, gy = r >> 4, gx = r & 15;
  float dn = dinv_at(gy, gx);
  float s = 0.f;
  {
    const float* nr = nodes + (size_t)n * 34;
    float hh = 0.f;
#pragma unroll
    for (int k = 0; k < 34; ++k) hh = fmaf(nr[k], gw[k * 32 + o], hh);
    s = hh * dn;
  }
  if (gy > 0) {
    const float* nr = nodes + (size_t)(n - 16) * 34;
    float hh = 0.f;
#pragma unroll
    for (int k = 0; k < 34; ++k) hh = fmaf(nr[k], gw[k * 32 + o], hh);
    s += hh * dinv_at(gy - 1, gx);
  }
  if (gy < 15) {
    const float* nr = nodes + (size_t)(n + 16) * 34;
    float hh = 0.f;
#pragma unroll
    for (int k = 0; k < 34; ++k) hh = fmaf(nr[k], gw[k * 32 + o], hh);
    s += hh * dinv_at(gy + 1, gx);
  }
  if (gx > 0) {
    const float* nr = nodes + (size_t)(n - 1) * 34;
    float hh = 0.f;
#pragma unroll
    for (int k = 0; k < 34; ++k) hh = fmaf(nr[k], gw[k * 32 + o], hh);
    s += hh * dinv_at(gy, gx - 1);
  }
  if (gx < 15) {
    const float* nr = nodes + (size_t)(n + 1) * 34;
    float hh = 0.f;
#pragma unroll
    for (int k = 0; k < 34; ++k) hh = fmaf(nr[k], gw[k * 32 + o], hh);
    s += hh * dinv_at(gy, gx + 1);
  }
  float g = dn * s + gcn_b[o];
  float mu = g;
  for (int m = 16; m; m >>= 1) mu += __shfl_xor(mu, m);
  mu *= (1.0f / 32.0f);
  float d = g - mu;
  float v = d * d;
  for (int m = 16; m; m >>= 1) v += __shfl_xor(v, m);
  v *= (1.0f / 32.0f);
  lnout[n * 32 + o] = d * rsqrtf(v + 1e-5f) * ln_g[o] + ln_b[o];
}

// K6: k-split 2-phase gate conv; weights LDS-resident; XCD-swizzled blocks.
__global__ __launch_bounds__(256) void fused_gate_mfma(
    const unsigned short* __restrict__ ycl, const float* __restrict__ mrs,
    const float* __restrict__ lnf, const unsigned short* __restrict__ wgF,
    const float* __restrict__ gate_b, const float* __restrict__ tpv,
    float* __restrict__ out) {
  __shared__ alignas(16) unsigned short comb[324 * 32];   // 20.7KB
  __shared__ alignas(16) unsigned short vvb[18 * 3 * 32]; // 3.4KB
  __shared__ alignas(16) unsigned short wl[9216];         // 18KB per-phase weights
  int blk = xcd_swz(blockIdx.x);
  int b = blk >> 8, r = blk & 255, gy = r >> 4, gx = r & 15;
  int tid = threadIdx.x;
  int wv = tid >> 6, lane = tid & 63;
  int lr = lane & 15, lg = lane >> 4;
  int y0 = gy * 16 - 1, x0 = gx * 16 - 1;
  const s16x8 z8 = (s16x8){0, 0, 0, 0, 0, 0, 0, 0};

  // ---- phase A staging: weights(p0) + conv half + vvb ----
  for (int i = tid; i < 1152; i += 256)
    *(s16x8*)&wl[i * 8] = *(const s16x8*)&wgF[i * 8];

  int i0 = tid, i1 = tid + 256;
  int row0 = i0 / 18, col0 = i0 - row0 * 18;
  int yy0_ = y0 + row0, xx0_ = x0 + col0;
  bool in0 = ((unsigned)yy0_ < 256u) && ((unsigned)xx0_ < 256u);
  int row1 = i1 / 18, col1 = i1 - row1 * 18;
  int yy1_ = y0 + row1, xx1_ = x0 + col1;
  bool in1 = (i1 < 324) && ((unsigned)yy1_ < 256u) && ((unsigned)xx1_ < 256u);
  const unsigned short* p0 = ycl + ((size_t)b * 65536 + (size_t)yy0_ * 256 + xx0_) * 32;
  const unsigned short* p1 = ycl + ((size_t)b * 65536 + (size_t)yy1_ * 256 + xx1_) * 32;
  s16x8 v0[4], v1[4];
#pragma unroll
  for (int h = 0; h < 4; ++h) v0[h] = in0 ? *(const s16x8*)&p0[h * 8] : z8;
#pragma unroll
  for (int h = 0; h < 4; ++h) v1[h] = in1 ? *(const s16x8*)&p1[h * 8] : z8;

  for (int i = tid; i < 1728; i += 256) {
    int row = i / 96, rem = i - row * 96, xc = rem >> 5, c = rem & 31;
    int yy = y0 + row;
    float uy = ((float)yy + 0.5f) * (1.f / 16.f) - 0.5f;
    float fy = floorf(uy);
    float ty = uy - fy;
    int iy0 = (int)fy;
    int iy0c = max(0, iy0), iy1c = min(15, iy0 + 1);
    int gxx = min(15, max(0, gx - 1 + xc));
    const float* base = lnf + (size_t)b * 8192 + c * 256;
    float a0 = base[iy0c * 16 + gxx], a1 = base[iy1c * 16 + gxx];
    vvb[i] = f2bf(a0 + ty * (a1 - a0));
  }

  {
    int sw0 = (i0 & 3) ^ ((i0 >> 2) & 3);
    int sw1 = (i1 & 3) ^ ((i1 >> 2) & 3);
#pragma unroll
    for (int h = 0; h < 4; ++h) {
      float f0[8], f1[8];
#pragma unroll
      for (int j = 0; j < 8; ++j) {
        float sc = mrs[b * 32 + h * 8 + j];
        float sh = mrs[512 + b * 32 + h * 8 + j];
        float a = bf2f((unsigned short)v0[h][j]) * sc + sh;
        f0[j] = a * sigmoidf_(a);
        float c = bf2f((unsigned short)v1[h][j]) * sc + sh;
        f1[j] = c * sigmoidf_(c);
      }
      *(s16x8*)&comb[i0 * 32 + (((h ^ sw0) & 3) << 3)] = pk8(f0);
      if (i1 < 324) *(s16x8*)&comb[i1 * 32 + (((h ^ sw1) & 3) << 3)] = pk8(f1);
    }
  }
  __syncthreads();  // barrier 1

  // ---- phase A MFMA: ic 0..31, weights from LDS ----
  f32x4 acc[4][2];
  float b0 = gate_b[lr], b1 = gate_b[16 + lr];
#pragma unroll
  for (int mi = 0; mi < 4; ++mi) {
    acc[mi][0] = (f32x4){b0, b0, b0, b0};
    acc[mi][1] = (f32x4){b1, b1, b1, b1};
  }
#pragma unroll
  for (int tap = 0; tap < 9; ++tap) {
    s16x8 wlo = *(const s16x8*)&wl[tap * 1024 + lane * 8];
    s16x8 whi = *(const s16x8*)&wl[tap * 1024 + 512 + lane * 8];
    int ky = tap / 3, kx = tap - ky * 3;
#pragma unroll
    for (int mi = 0; mi < 4; ++mi) {
      int s = (wv * 4 + mi + ky) * 18 + lr + kx;
      s16x8 a = *(const s16x8*)&comb[s * 32 + ((lg ^ (s & 3) ^ ((s >> 2) & 3)) << 3)];
      acc[mi][0] = __builtin_amdgcn_mfma_f32_16x16x32_bf16(a, wlo, acc[mi][0], 0, 0, 0);
      acc[mi][1] = __builtin_amdgcn_mfma_f32_16x16x32_bf16(a, whi, acc[mi][1], 0, 0, 0);
    }
  }

  // save cf centers before comb is overwritten
  unsigned cfp[4][2][2];
#pragma unroll
  for (int mi = 0; mi < 4; ++mi) {
    int m = wv * 4 + mi;
#pragma unroll
    for (int nt = 0; nt < 2; ++nt) {
      int oct = nt * 2 + (lr >> 3), el = lr & 7;
#pragma unroll
      for (int rh = 0; rh < 2; ++rh) {
        int px0 = lg * 4 + rh * 2, px1 = px0 + 1;
        int s0 = (m + 1) * 18 + px0 + 1, s1 = (m + 1) * 18 + px1 + 1;
        unsigned lo = comb[s0 * 32 + ((oct ^ (s0 & 3) ^ ((s0 >> 2) & 3)) << 3) + el];
        unsigned hi = comb[s1 * 32 + ((oct ^ (s1 & 3) ^ ((s1 >> 2) & 3)) << 3) + el];
        cfp[mi][nt][rh] = lo | (hi << 16);
      }
    }
  }
  __syncthreads();  // barrier 2

  // ---- phase B staging: weights(p1) + gcn half ----
  for (int i = tid; i < 1152; i += 256)
    *(s16x8*)&wl[i * 8] = *(const s16x8*)&wgF[9216 + i * 8];

  for (int i = tid; i < 324; i += 256) {
    int row = i / 18, col = i - row * 18;
    int yy = y0 + row, xx = x0 + col;
    int swa = (i & 3) ^ ((i >> 2) & 3);
    if (((unsigned)yy < 256u) && ((unsigned)xx < 256u)) {
      float ux = ((float)xx + 0.5f) * (1.f / 16.f) - 0.5f;
      float fx = floorf(ux);
      float tx = ux - fx;
      int dx0 = (int)fx - (gx - 1);   // in {0,1}
      const unsigned short* va = &vvb[(row * 3 + dx0) * 32];
      const unsigned short* vb = va + 32;
#pragma unroll
      for (int h = 0; h < 4; ++h) {
        s16x8 av = *(const s16x8*)&va[h * 8];
        s16x8 bv = *(const s16x8*)&vb[h * 8];
        float f[8];
#pragma unroll
        for (int j = 0; j < 8; ++j) {
          float a = bf2f((unsigned short)av[j]);
          f[j] = a + tx * (bf2f((unsigned short)bv[j]) - a);
        }
        *(s16x8*)&comb[i * 32 + (((h ^ swa) & 3) << 3)] = pk8(f);
      }
    } else {
#pragma unroll
      for (int h = 0; h < 4; ++h) *(s16x8*)&comb[i * 32 + (((h ^ swa) & 3) << 3)] = z8;
    }
  }
  __syncthreads();  // barrier 3

  // ---- phase B MFMA: ic 32..63 ----
#pragma unroll
  for (int tap = 0; tap < 9; ++tap) {
    s16x8 wlo = *(const s16x8*)&wl[tap * 1024 + lane * 8];
    s16x8 whi = *(const s16x8*)&wl[tap * 1024 + 512 + lane * 8];
    int ky = tap / 3, kx = tap - ky * 3;
#pragma unroll
    for (int mi = 0; mi < 4; ++mi) {
      int s = (wv * 4 + mi + ky) * 18 + lr + kx;
      s16x8 a = *(const s16x8*)&comb[s * 32 + ((lg ^ (s & 3) ^ ((s >> 2) & 3)) << 3)];
      acc[mi][0] = __builtin_amdgcn_mfma_f32_16x16x32_bf16(a, wlo, acc[mi][0], 0, 0, 0);
      acc[mi][1] = __builtin_amdgcn_mfma_f32_16x16x32_bf16(a, whi, acc[mi][1], 0, 0, 0);
    }
  }

  // ---- epilogue ----
#pragma unroll
  for (int mi = 0; mi < 4; ++mi) {
    int m = wv * 4 + mi;
#pragma unroll
    for (int nt = 0; nt < 2; ++nt) {
      int o = nt * 16 + lr;
      int oct = nt * 2 + (lr >> 3), el = lr & 7;
      f32x4 a = acc[mi][nt];
      float gamma = tpv[b * 64 + o] + 1.0f, beta = tpv[b * 64 + 32 + o];
      f32x4 res;
#pragma unroll
      for (int rr = 0; rr < 4; ++rr) {
        int px = lg * 4 + rr;
        int s = (m + 1) * 18 + px + 1;
        unsigned cfu = cfp[mi][nt][rr >> 1];
        float cf = bf2f((unsigned short)((rr & 1) ? (cfu >> 16) : (cfu & 0xffff)));
        float gu = bf2f(comb[s * 32 + ((oct ^ (s & 3) ^ ((s >> 2) & 3)) << 3) + el]);
        float gate = sigmoidf_(a[rr]);
        float merged = gate * cf + (1.f - gate) * gu;
        res[rr] = merged * gamma + beta;
      }
      *(f32x4*)&out[((size_t)(b * 32 + o)) * 65536 + (size_t)(gy * 16 + m) * 256 + gx * 16 + lg * 4] = res;
    }
  }
}

extern "C" void kernel_launch(void* const* d_in, const int* in_sizes, int n_in,
                              void* d_out, int out_size, void* d_ws, size_t ws_size,
                              hipStream_t stream) {
  const float* x      = (const float*)d_in[0];
  const float* t      = (const float*)d_in[1];
  const float* conv_w = (const float*)d_in[2];
  const float* conv_b = (const float*)d_in[3];
  const float* gn_g   = (const float*)d_in[4];
  const float* gn_b   = (const float*)d_in[5];
  const float* gcn_w  = (const float*)d_in[6];
  const float* gcn_b  = (const float*)d_in[7];
  const float* ln_g   = (const float*)d_in[8];
  const float* ln_b   = (const float*)d_in[9];
  const float* gate_w = (const float*)d_in[10];
  const float* gate_b = (const float*)d_in[11];
  const float* tp_w   = (const float*)d_in[12];
  const float* tp_b   = (const float*)d_in[13];

  float* ws = (float*)d_ws;
  unsigned short* ycl = (unsigned short*)ws;        // 33,554,432 u16
  float* st    = ws + 16777216;                     // 256
  float* mrs   = st + 256;                          // 1024
  float* nodes = mrs + 1024;                        // 139,264
  float* lnf   = nodes + 139264;                    // 131,072
  float* tpv   = lnf + 131072;                      // 1,024
  unsigned short* wcF = (unsigned short*)(tpv + 1024);   // 9,216 u16
  unsigned short* wgF = wcF + 9216;                 // 18,432 u16

  hipMemsetAsync(st, 0, 256 * sizeof(float), stream);
  prep_misc<<<76, 256, 0, stream>>>(conv_w, gate_w, t, tp_w, tp_b, wcF, wgF, tpv);
  conv1_mfma<<<4096, 256, 0, stream>>>(x, wcF, conv_b, ycl, st, nodes);
  gn_finalize<<<1, 512, 0, stream>>>(st, gn_g, gn_b, mrs);
  gcn_fused<<<2048, 64, 0, stream>>>(nodes, gcn_w, gcn_b, ln_g, ln_b, lnf);
  fused_gate_mfma<<<4096, 256, 0, stream>>>(ycl, mrs, lnf, wgF, gate_b, tpv,
                                            (float*)d_out);
}

// Round 14
// 203.157 us; speedup vs baseline: 1.3756x; 1.0415x over previous
//
#include <hip/hip_runtime.h>
#include <hip/hip_bf16.h>
#include <math.h>

typedef __attribute__((ext_vector_type(4))) float f32x4;
typedef __attribute__((ext_vector_type(8))) short s16x8;
typedef __attribute__((ext_vector_type(4))) short s16x4;

static __device__ __forceinline__ float sigmoidf_(float v) { return 1.0f / (1.0f + __expf(-v)); }
static __device__ __forceinline__ unsigned short f2bf(float f) {
  unsigned u = __float_as_uint(f);
  u += 0x7fffu + ((u >> 16) & 1u);
  return (unsigned short)(u >> 16);
}
static __device__ __forceinline__ float bf2f(unsigned short h) {
  return __uint_as_float(((unsigned)h) << 16);
}
static __device__ __forceinline__ s16x4 pk4(float a, float b, float c, float d) {
  union { __hip_bfloat162 h2[2]; s16x4 v; } u;
  u.h2[0] = __float22bfloat162_rn(make_float2(a, b));
  u.h2[1] = __float22bfloat162_rn(make_float2(c, d));
  return u.v;
}
static __device__ __forceinline__ s16x8 pk8(const float* f) {
  union { __hip_bfloat162 h2[4]; s16x8 v; } u;
  u.h2[0] = __float22bfloat162_rn(make_float2(f[0], f[1]));
  u.h2[1] = __float22bfloat162_rn(make_float2(f[2], f[3]));
  u.h2[2] = __float22bfloat162_rn(make_float2(f[4], f[5]));
  u.h2[3] = __float22bfloat162_rn(make_float2(f[6], f[7]));
  return u.v;
}
// XCD-aware swizzle: each XCD gets a contiguous 512-block chunk (2 images).
static __device__ __forceinline__ int xcd_swz(int id) {
  return (id & 7) * 512 + (id >> 3);
}

// K0: weight fragments in LANE ORDER + tproj.
__global__ __launch_bounds__(256) void prep_misc(const float* __restrict__ cw,
                                                 const float* __restrict__ gw,
                                                 const float* __restrict__ t,
                                                 const float* __restrict__ tw,
                                                 const float* __restrict__ tb,
                                                 unsigned short* __restrict__ wcF,
                                                 unsigned short* __restrict__ wgF,
                                                 float* __restrict__ tpo) {
  int blk = blockIdx.x;
  if (blk < 72) {
    int i = blk * 256 + threadIdx.x;
    if (i < 9216) {
      int j = i & 7, lane = (i >> 3) & 63, f = (i >> 9) & 1, tap = i >> 10;
      int o = f * 16 + (lane & 15), c = (lane >> 4) * 8 + j;
      wcF[i] = f2bf(cw[(o * 32 + c) * 9 + tap]);
    }
    if (i < 18432) {
      int j = i & 7, lane = (i >> 3) & 63, f = (i >> 9) & 1;
      int rem = i >> 10;               // 0..17
      int tap = rem % 9, p = rem / 9;
      int o = f * 16 + (lane & 15), ic = p * 32 + (lane >> 4) * 8 + j;
      wgF[i] = f2bf(gw[(o * 64 + ic) * 9 + tap]);
    }
  } else {
    int idx = (blk - 72) * 256 + threadIdx.x;  // < 1024
    int b = idx >> 6, j = idx & 63;
    const float* tr = t + b * 256;
    const float* wr = tw + j * 256;
    float s = tb[j];
    for (int k = 0; k < 256; ++k) s = fmaf(tr[k], wr[k], s);
    tpo[idx] = s;
  }
}

// K1: conv3x3 MFMA, 512 threads / 8 waves (2 rows each); weights LDS-resident;
// XCD-swizzled; gpart overlaid on xt (LDS 39.2KB -> 4 blocks/CU).
__global__ __launch_bounds__(512) void conv1_mfma(const float* __restrict__ x,
                                                  const unsigned short* __restrict__ wcF,
                                                  const float* __restrict__ conv_b,
                                                  unsigned short* __restrict__ ycl,
                                                  float* __restrict__ stats,
                                                  float* __restrict__ nodes) {
  __shared__ alignas(16) unsigned short xt[324 * 32];   // 20.7KB
  __shared__ alignas(16) unsigned short wl[9216];       // 18KB weight fragments
  int blk = xcd_swz(blockIdx.x);
  int b = blk >> 8, r = blk & 255, gy = r >> 4, gx = r & 15;
  int tid = threadIdx.x;
  int y0 = gy * 16 - 1, x0 = gx * 16 - 1;
  for (int i = tid; i < 1152; i += 512)
    *(s16x8*)&wl[i * 8] = *(const s16x8*)&wcF[i * 8];
  for (int i = tid; i < 2592; i += 512) {
    int q = i / 324, s = i - q * 324;
    int row = s / 18, col = s - row * 18;
    int yy = y0 + row, xx = x0 + col;
    float v0 = 0, v1 = 0, v2 = 0, v3 = 0;
    if ((unsigned)yy < 256u && (unsigned)xx < 256u) {
      const float* p = x + ((size_t)(b * 32 + q * 4)) * 65536 + yy * 256 + xx;
      v0 = p[0]; v1 = p[65536]; v2 = p[131072]; v3 = p[196608];
    }
    int slot = (q >> 1) ^ (s & 3) ^ ((s >> 2) & 3);
    int off = s * 32 + slot * 8 + (q & 1) * 4;
    *(s16x4*)&xt[off] = pk4(v0, v1, v2, v3);
  }
  __syncthreads();

  int wv = tid >> 6, lane = tid & 63;
  int lr = lane & 15, lg = lane >> 4;

  // fused patch means: wave wv -> channels wv*4..wv*4+3; p = pp*64+lane (bank-friendly)
#pragma unroll
  for (int cc = 0; cc < 4; ++cc) {
    int c = wv * 4 + cc;
    int q = c >> 2, jj = c & 3;
    float s = 0.f;
#pragma unroll
    for (int pp = 0; pp < 4; ++pp) {
      int p = pp * 64 + lane;
      int sp = ((p >> 4) + 1) * 18 + (p & 15) + 1;
      int off = sp * 32 + (((q >> 1) ^ (sp & 3) ^ ((sp >> 2) & 3)) << 3) + (q & 1) * 4 + jj;
      s += bf2f(xt[off]);
    }
    for (int m = 1; m < 64; m <<= 1) s += __shfl_xor(s, m);
    if (lane == 0) nodes[(size_t)blk * 34 + c] = s * (1.f / 256.f);
  }
  if (tid == 0) {
    nodes[(size_t)blk * 34 + 32] = (float)gy * (1.f / 16.f);
    nodes[(size_t)blk * 34 + 33] = (float)gx * (1.f / 16.f);
  }

  // MFMA: A=weights (LDS), B=pixels. Wave wv covers rows wv*2, wv*2+1.
  f32x4 acc[2][2];
  f32x4 cb0 = *(const f32x4*)&conv_b[lg * 4];
  f32x4 cb1 = *(const f32x4*)&conv_b[16 + lg * 4];
#pragma unroll
  for (int mi = 0; mi < 2; ++mi) { acc[mi][0] = cb0; acc[mi][1] = cb1; }
#pragma unroll
  for (int tap = 0; tap < 9; ++tap) {
    s16x8 wf0 = *(const s16x8*)&wl[tap * 1024 + lane * 8];
    s16x8 wf1 = *(const s16x8*)&wl[tap * 1024 + 512 + lane * 8];
    int ky = tap / 3, kx = tap - ky * 3;
#pragma unroll
    for (int mi = 0; mi < 2; ++mi) {
      int s = (wv * 2 + mi + ky) * 18 + lr + kx;
      int offB = s * 32 + ((lg ^ (s & 3) ^ ((s >> 2) & 3)) << 3);
      s16x8 xf = *(const s16x8*)&xt[offB];
      acc[mi][0] = __builtin_amdgcn_mfma_f32_16x16x32_bf16(wf0, xf, acc[mi][0], 0, 0, 0);
      acc[mi][1] = __builtin_amdgcn_mfma_f32_16x16x32_bf16(wf1, xf, acc[mi][1], 0, 0, 0);
    }
  }
  // epilogue: channel-last store
#pragma unroll
  for (int mi = 0; mi < 2; ++mi) {
    int oy = gy * 16 + wv * 2 + mi;
    size_t pixbase = ((size_t)b * 65536 + (size_t)oy * 256 + gx * 16 + lr) * 32;
#pragma unroll
    for (int nt = 0; nt < 2; ++nt) {
      f32x4 a = acc[mi][nt];
      *(s16x4*)&ycl[pixbase + nt * 16 + lg * 4] = pk4(a[0], a[1], a[2], a[3]);
    }
  }
  // fused GN stats — gpart overlaid on xt (all xt reads done; barrier first)
  __syncthreads();
  float* gpart = (float*)xt;  // [g][which][wv] = [(g*2+which)*8 + wv]
#pragma unroll
  for (int nt = 0; nt < 2; ++nt) {
    float s = 0.f, q = 0.f;
#pragma unroll
    for (int mi = 0; mi < 2; ++mi)
#pragma unroll
      for (int rr = 0; rr < 4; ++rr) {
        float v = acc[mi][nt][rr];
        s += v; q += v * v;
      }
    for (int m = 1; m < 16; m <<= 1) { s += __shfl_xor(s, m); q += __shfl_xor(q, m); }
    if (lr == 0) {
      int g = nt * 4 + lg;
      gpart[(g * 2 + 0) * 8 + wv] = s;
      gpart[(g * 2 + 1) * 8 + wv] = q;
    }
  }
  __syncthreads();
  if (tid < 16) {
    int g = tid >> 1, which = tid & 1;
    float v = 0.f;
#pragma unroll
    for (int w = 0; w < 8; ++w) v += gpart[(g * 2 + which) * 8 + w];
    atomicAdd(&stats[(which ? 128 : 0) + b * 8 + g], v);
  }
}

// K2: fold GN into per-(b,c) scale/shift
__global__ void gn_finalize(const float* __restrict__ stats,
                            const float* __restrict__ gn_g,
                            const float* __restrict__ gn_b,
                            float* __restrict__ mrs) {
  int i = threadIdx.x;  // 512
  int b = i >> 5, c = i & 31, g = c >> 2;
  float s = stats[b * 8 + g], q = stats[128 + b * 8 + g];
  const float n = 262144.f;
  float mean = s / n;
  float var = q / n - mean * mean;
  float rs = rsqrtf(var + 1e-5f);
  float scale = rs * gn_g[c];
  mrs[i] = scale;
  mrs[512 + i] = gn_b[c] - mean * scale;
}

__device__ __forceinline__ float dinv_at(int gy, int gx) {
  return rsqrtf((float)(1 + (gy > 0) + (gy < 15) + (gx > 0) + (gx < 15)));
}

// K3: fused GCN
__global__ __launch_bounds__(64) void gcn_fused(const float* __restrict__ nodes,
                                                const float* __restrict__ gw,
                                                const float* __restrict__ gcn_b,
                                                const float* __restrict__ ln_g,
                                                const float* __restrict__ ln_b,
                                                float* __restrict__ lnout) {
  int n = blockIdx.x * 2 + (threadIdx.x >> 5);
  int o = threadIdx.x & 31;
  int r = n & 255, gy = r >> 4, gx = r & 15;
  float dn = dinv_at(gy, gx);
  float s = 0.f;
  {
    const float* nr = nodes + (size_t)n * 34;
    float hh = 0.f;
#pragma unroll
    for (int k = 0; k < 34; ++k) hh = fmaf(nr[k], gw[k * 32 + o], hh);
    s = hh * dn;
  }
  if (gy > 0) {
    const float* nr = nodes + (size_t)(n - 16) * 34;
    float hh = 0.f;
#pragma unroll
    for (int k = 0; k < 34; ++k) hh = fmaf(nr[k], gw[k * 32 + o], hh);
    s += hh * dinv_at(gy - 1, gx);
  }
  if (gy < 15) {
    const float* nr = nodes + (size_t)(n + 16) * 34;
    float hh = 0.f;
#pragma unroll
    for (int k = 0; k < 34; ++k) hh = fmaf(nr[k], gw[k * 32 + o], hh);
    s += hh * dinv_at(gy + 1, gx);
  }
  if (gx > 0) {
    const float* nr = nodes + (size_t)(n - 1) * 34;
    float hh = 0.f;
#pragma unroll
    for (int k = 0; k < 34; ++k) hh = fmaf(nr[k], gw[k * 32 + o], hh);
    s += hh * dinv_at(gy, gx - 1);
  }
  if (gx < 15) {
    const float* nr = nodes + (size_t)(n + 1) * 34;
    float hh = 0.f;
#pragma unroll
    for (int k = 0; k < 34; ++k) hh = fmaf(nr[k], gw[k * 32 + o], hh);
    s += hh * dinv_at(gy, gx + 1);
  }
  float g = dn * s + gcn_b[o];
  float mu = g;
  for (int m = 16; m; m >>= 1) mu += __shfl_xor(mu, m);
  mu *= (1.0f / 32.0f);
  float d = g - mu;
  float v = d * d;
  for (int m = 16; m; m >>= 1) v += __shfl_xor(v, m);
  v *= (1.0f / 32.0f);
  lnout[n * 32 + o] = d * rsqrtf(v + 1e-5f) * ln_g[o] + ln_b[o];
}

// K6: k-split 2-phase gate conv, 512 threads / 8 waves (2 rows each);
// weights LDS-resident per phase; XCD-swizzled. LDS 42.6KB -> 3 blocks x 8 waves.
__global__ __launch_bounds__(512) void fused_gate_mfma(
    const unsigned short* __restrict__ ycl, const float* __restrict__ mrs,
    const float* __restrict__ lnf, const unsigned short* __restrict__ wgF,
    const float* __restrict__ gate_b, const float* __restrict__ tpv,
    float* __restrict__ out) {
  __shared__ alignas(16) unsigned short comb[324 * 32];   // 20.7KB
  __shared__ alignas(16) unsigned short vvb[18 * 3 * 32]; // 3.4KB
  __shared__ alignas(16) unsigned short wl[9216];         // 18KB per-phase weights
  int blk = xcd_swz(blockIdx.x);
  int b = blk >> 8, r = blk & 255, gy = r >> 4, gx = r & 15;
  int tid = threadIdx.x;
  int wv = tid >> 6, lane = tid & 63;
  int lr = lane & 15, lg = lane >> 4;
  int y0 = gy * 16 - 1, x0 = gx * 16 - 1;
  const s16x8 z8 = (s16x8){0, 0, 0, 0, 0, 0, 0, 0};

  // ---- phase A staging: weights(p0) + conv half + vvb ----
  for (int i = tid; i < 1152; i += 512)
    *(s16x8*)&wl[i * 8] = *(const s16x8*)&wgF[i * 8];

  int row0 = tid / 18, col0 = tid - row0 * 18;
  int yy0_ = y0 + row0, xx0_ = x0 + col0;
  bool act = tid < 324;
  bool in0 = act && ((unsigned)yy0_ < 256u) && ((unsigned)xx0_ < 256u);
  const unsigned short* p0 = ycl + ((size_t)b * 65536 + (size_t)yy0_ * 256 + xx0_) * 32;
  s16x8 v0[4];
#pragma unroll
  for (int h = 0; h < 4; ++h) v0[h] = in0 ? *(const s16x8*)&p0[h * 8] : z8;

  for (int i = tid; i < 1728; i += 512) {
    int row = i / 96, rem = i - row * 96, xc = rem >> 5, c = rem & 31;
    int yy = y0 + row;
    float uy = ((float)yy + 0.5f) * (1.f / 16.f) - 0.5f;
    float fy = floorf(uy);
    float ty = uy - fy;
    int iy0 = (int)fy;
    int iy0c = max(0, iy0), iy1c = min(15, iy0 + 1);
    int gxx = min(15, max(0, gx - 1 + xc));
    const float* base = lnf + (size_t)b * 8192 + c * 256;
    float a0 = base[iy0c * 16 + gxx], a1 = base[iy1c * 16 + gxx];
    vvb[i] = f2bf(a0 + ty * (a1 - a0));
  }

  if (act) {
    int sw0 = (tid & 3) ^ ((tid >> 2) & 3);
#pragma unroll
    for (int h = 0; h < 4; ++h) {
      float f0[8];
#pragma unroll
      for (int j = 0; j < 8; ++j) {
        float sc = mrs[b * 32 + h * 8 + j];
        float sh = mrs[512 + b * 32 + h * 8 + j];
        float a = bf2f((unsigned short)v0[h][j]) * sc + sh;
        f0[j] = a * sigmoidf_(a);
      }
      *(s16x8*)&comb[tid * 32 + (((h ^ sw0) & 3) << 3)] = pk8(f0);
    }
  }
  __syncthreads();  // barrier 1

  // ---- phase A MFMA: ic 0..31 ----
  f32x4 acc[2][2];
  float b0 = gate_b[lr], b1 = gate_b[16 + lr];
#pragma unroll
  for (int mi = 0; mi < 2; ++mi) {
    acc[mi][0] = (f32x4){b0, b0, b0, b0};
    acc[mi][1] = (f32x4){b1, b1, b1, b1};
  }
#pragma unroll
  for (int tap = 0; tap < 9; ++tap) {
    s16x8 wlo = *(const s16x8*)&wl[tap * 1024 + lane * 8];
    s16x8 whi = *(const s16x8*)&wl[tap * 1024 + 512 + lane * 8];
    int ky = tap / 3, kx = tap - ky * 3;
#pragma unroll
    for (int mi = 0; mi < 2; ++mi) {
      int s = (wv * 2 + mi + ky) * 18 + lr + kx;
      s16x8 a = *(const s16x8*)&comb[s * 32 + ((lg ^ (s & 3) ^ ((s >> 2) & 3)) << 3)];
      acc[mi][0] = __builtin_amdgcn_mfma_f32_16x16x32_bf16(a, wlo, acc[mi][0], 0, 0, 0);
      acc[mi][1] = __builtin_amdgcn_mfma_f32_16x16x32_bf16(a, whi, acc[mi][1], 0, 0, 0);
    }
  }

  // save cf centers before comb is overwritten
  unsigned cfp[2][2][2];
#pragma unroll
  for (int mi = 0; mi < 2; ++mi) {
    int m = wv * 2 + mi;
#pragma unroll
    for (int nt = 0; nt < 2; ++nt) {
      int oct = nt * 2 + (lr >> 3), el = lr & 7;
#pragma unroll
      for (int rh = 0; rh < 2; ++rh) {
        int px0 = lg * 4 + rh * 2, px1 = px0 + 1;
        int s0 = (m + 1) * 18 + px0 + 1, s1 = (m + 1) * 18 + px1 + 1;
        unsigned lo = comb[s0 * 32 + ((oct ^ (s0 & 3) ^ ((s0 >> 2) & 3)) << 3) + el];
        unsigned hi = comb[s1 * 32 + ((oct ^ (s1 & 3) ^ ((s1 >> 2) & 3)) << 3) + el];
        cfp[mi][nt][rh] = lo | (hi << 16);
      }
    }
  }
  __syncthreads();  // barrier 2

  // ---- phase B staging: weights(p1) + gcn half ----
  for (int i = tid; i < 1152; i += 512)
    *(s16x8*)&wl[i * 8] = *(const s16x8*)&wgF[9216 + i * 8];

  if (act) {
    int swa = (tid & 3) ^ ((tid >> 2) & 3);
    if (((unsigned)yy0_ < 256u) && ((unsigned)xx0_ < 256u)) {
      float ux = ((float)xx0_ + 0.5f) * (1.f / 16.f) - 0.5f;
      float fx = floorf(ux);
      float tx = ux - fx;
      int dx0 = (int)fx - (gx - 1);   // in {0,1}
      const unsigned short* va = &vvb[(row0 * 3 + dx0) * 32];
      const unsigned short* vb = va + 32;
#pragma unroll
      for (int h = 0; h < 4; ++h) {
        s16x8 av = *(const s16x8*)&va[h * 8];
        s16x8 bv = *(const s16x8*)&vb[h * 8];
        float f[8];
#pragma unroll
        for (int j = 0; j < 8; ++j) {
          float a = bf2f((unsigned short)av[j]);
          f[j] = a + tx * (bf2f((unsigned short)bv[j]) - a);
        }
        *(s16x8*)&comb[tid * 32 + (((h ^ swa) & 3) << 3)] = pk8(f);
      }
    } else {
#pragma unroll
      for (int h = 0; h < 4; ++h) *(s16x8*)&comb[tid * 32 + (((h ^ swa) & 3) << 3)] = z8;
    }
  }
  __syncthreads();  // barrier 3

  // ---- phase B MFMA: ic 32..63 ----
#pragma unroll
  for (int tap = 0; tap < 9; ++tap) {
    s16x8 wlo = *(const s16x8*)&wl[tap * 1024 + lane * 8];
    s16x8 whi = *(const s16x8*)&wl[tap * 1024 + 512 + lane * 8];
    int ky = tap / 3, kx = tap - ky * 3;
#pragma unroll
    for (int mi = 0; mi < 2; ++mi) {
      int s = (wv * 2 + mi + ky) * 18 + lr + kx;
      s16x8 a = *(const s16x8*)&comb[s * 32 + ((lg ^ (s & 3) ^ ((s >> 2) & 3)) << 3)];
      acc[mi][0] = __builtin_amdgcn_mfma_f32_16x16x32_bf16(a, wlo, acc[mi][0], 0, 0, 0);
      acc[mi][1] = __builtin_amdgcn_mfma_f32_16x16x32_bf16(a, whi, acc[mi][1], 0, 0, 0);
    }
  }

  // ---- epilogue ----
#pragma unroll
  for (int mi = 0; mi < 2; ++mi) {
    int m = wv * 2 + mi;
#pragma unroll
    for (int nt = 0; nt < 2; ++nt) {
      int o = nt * 16 + lr;
      int oct = nt * 2 + (lr >> 3), el = lr & 7;
      f32x4 a = acc[mi][nt];
      float gamma = tpv[b * 64 + o] + 1.0f, beta = tpv[b * 64 + 32 + o];
      f32x4 res;
#pragma unroll
      for (int rr = 0; rr < 4; ++rr) {
        int px = lg * 4 + rr;
        int s = (m + 1) * 18 + px + 1;
        unsigned cfu = cfp[mi][nt][rr >> 1];
        float cf = bf2f((unsigned short)((rr & 1) ? (cfu >> 16) : (cfu & 0xffff)));
        float gu = bf2f(comb[s * 32 + ((oct ^ (s & 3) ^ ((s >> 2) & 3)) << 3) + el]);
        float gate = sigmoidf_(a[rr]);
        float merged = gate * cf + (1.f - gate) * gu;
        res[rr] = merged * gamma + beta;
      }
      *(f32x4*)&out[((size_t)(b * 32 + o)) * 65536 + (size_t)(gy * 16 + m) * 256 + gx * 16 + lg * 4] = res;
    }
  }
}

extern "C" void kernel_launch(void* const* d_in, const int* in_sizes, int n_in,
                              void* d_out, int out_size, void* d_ws, size_t ws_size,
                              hipStream_t stream) {
  const float* x      = (const float*)d_in[0];
  const float* t      = (const float*)d_in[1];
  const float* conv_w = (const float*)d_in[2];
  const float* conv_b = (const float*)d_in[3];
  const float* gn_g   = (const float*)d_in[4];
  const float* gn_b   = (const float*)d_in[5];
  const float* gcn_w  = (const float*)d_in[6];
  const float* gcn_b  = (const float*)d_in[7];
  const float* ln_g   = (const float*)d_in[8];
  const float* ln_b   = (const float*)d_in[9];
  const float* gate_w = (const float*)d_in[10];
  const float* gate_b = (const float*)d_in[11];
  const float* tp_w   = (const float*)d_in[12];
  const float* tp_b   = (const float*)d_in[13];

  float* ws = (float*)d_ws;
  unsigned short* ycl = (unsigned short*)ws;        // 33,554,432 u16
  float* st    = ws + 16777216;                     // 256
  float* mrs   = st + 256;                          // 1024
  float* nodes = mrs + 1024;                        // 139,264
  float* lnf   = nodes + 139264;                    // 131,072
  float* tpv   = lnf + 131072;                      // 1,024
  unsigned short* wcF = (unsigned short*)(tpv + 1024);   // 9,216 u16
  unsigned short* wgF = wcF + 9216;                 // 18,432 u16

  hipMemsetAsync(st, 0, 256 * sizeof(float), stream);
  prep_misc<<<76, 256, 0, stream>>>(conv_w, gate_w, t, tp_w, tp_b, wcF, wgF, tpv);
  conv1_mfma<<<4096, 512, 0, stream>>>(x, wcF, conv_b, ycl, st, nodes);
  gn_finalize<<<1, 512, 0, stream>>>(st, gn_g, gn_b, mrs);
  gcn_fused<<<2048, 64, 0, stream>>>(nodes, gcn_w, gcn_b, ln_g, ln_b, lnf);
  fused_gate_mfma<<<4096, 512, 0, stream>>>(ycl, mrs, lnf, wgF, gate_b, tpv,
                                            (float*)d_out);
}

// Round 15
// 201.993 us; speedup vs baseline: 1.3835x; 1.0058x over previous
//
#include <hip/hip_runtime.h>
#include <hip/hip_bf16.h>
#include <math.h>

typedef __attribute__((ext_vector_type(4))) float f32x4;
typedef __attribute__((ext_vector_type(8))) short s16x8;
typedef __attribute__((ext_vector_type(4))) short s16x4;

static __device__ __forceinline__ float sigmoidf_(float v) { return 1.0f / (1.0f + __expf(-v)); }
static __device__ __forceinline__ unsigned short f2bf(float f) {
  unsigned u = __float_as_uint(f);
  u += 0x7fffu + ((u >> 16) & 1u);
  return (unsigned short)(u >> 16);
}
static __device__ __forceinline__ float bf2f(unsigned short h) {
  return __uint_as_float(((unsigned)h) << 16);
}
static __device__ __forceinline__ s16x4 pk4(float a, float b, float c, float d) {
  union { __hip_bfloat162 h2[2]; s16x4 v; } u;
  u.h2[0] = __float22bfloat162_rn(make_float2(a, b));
  u.h2[1] = __float22bfloat162_rn(make_float2(c, d));
  return u.v;
}
static __device__ __forceinline__ s16x8 pk8(const float* f) {
  union { __hip_bfloat162 h2[4]; s16x8 v; } u;
  u.h2[0] = __float22bfloat162_rn(make_float2(f[0], f[1]));
  u.h2[1] = __float22bfloat162_rn(make_float2(f[2], f[3]));
  u.h2[2] = __float22bfloat162_rn(make_float2(f[4], f[5]));
  u.h2[3] = __float22bfloat162_rn(make_float2(f[6], f[7]));
  return u.v;
}
// XCD-aware swizzle: each XCD gets a contiguous 512-block chunk (2 images).
static __device__ __forceinline__ int xcd_swz(int id) {
  return (id & 7) * 512 + (id >> 3);
}
#define NLOG2E -1.44269504f

// K0: weight fragments in LANE ORDER (gate weights prescaled by -log2e) + tproj + gbs.
__global__ __launch_bounds__(256) void prep_misc(const float* __restrict__ cw,
                                                 const float* __restrict__ gw,
                                                 const float* __restrict__ t,
                                                 const float* __restrict__ tw,
                                                 const float* __restrict__ tb,
                                                 const float* __restrict__ gb,
                                                 unsigned short* __restrict__ wcF,
                                                 unsigned short* __restrict__ wgF,
                                                 float* __restrict__ tpo,
                                                 float* __restrict__ gbs) {
  int blk = blockIdx.x;
  if (blk < 72) {
    int i = blk * 256 + threadIdx.x;
    if (i < 9216) {
      int j = i & 7, lane = (i >> 3) & 63, f = (i >> 9) & 1, tap = i >> 10;
      int o = f * 16 + (lane & 15), c = (lane >> 4) * 8 + j;
      wcF[i] = f2bf(cw[(o * 32 + c) * 9 + tap]);
    }
    if (i < 18432) {
      int j = i & 7, lane = (i >> 3) & 63, f = (i >> 9) & 1;
      int rem = i >> 10;               // 0..17
      int tap = rem % 9, p = rem / 9;
      int o = f * 16 + (lane & 15), ic = p * 32 + (lane >> 4) * 8 + j;
      wgF[i] = f2bf(gw[(o * 64 + ic) * 9 + tap] * NLOG2E);
    }
  } else {
    int idx = (blk - 72) * 256 + threadIdx.x;  // < 1024
    int b = idx >> 6, j = idx & 63;
    const float* tr = t + b * 256;
    const float* wr = tw + j * 256;
    float s = tb[j];
    for (int k = 0; k < 256; ++k) s = fmaf(tr[k], wr[k], s);
    tpo[idx] = s;
    if (blk == 75 && threadIdx.x < 32) gbs[threadIdx.x] = gb[threadIdx.x] * NLOG2E;
  }
}

// K1: conv3x3 MFMA, 512 threads / 8 waves; weights LDS-resident; XCD-swizzled.
// Staging: fixed q per 64-lane group (one base pointer, no div-by-324).
__global__ __launch_bounds__(512) void conv1_mfma(const float* __restrict__ x,
                                                  const unsigned short* __restrict__ wcF,
                                                  const float* __restrict__ conv_b,
                                                  unsigned short* __restrict__ ycl,
                                                  float* __restrict__ stats,
                                                  float* __restrict__ nodes) {
  __shared__ alignas(16) unsigned short xt[324 * 32];   // 20.7KB (XOR-swizzled)
  __shared__ alignas(16) unsigned short wl[9216];       // 18KB weight fragments
  int blk = xcd_swz(blockIdx.x);
  int b = blk >> 8, r = blk & 255, gy = r >> 4, gx = r & 15;
  int tid = threadIdx.x;
  int y0 = gy * 16 - 1, x0 = gx * 16 - 1;
  for (int i = tid; i < 1152; i += 512)
    *(s16x8*)&wl[i * 8] = *(const s16x8*)&wcF[i * 8];
  {
    int q = tid >> 6, sl = tid & 63;
    const float* bp = x + ((size_t)(b * 32 + q * 4)) * 65536;
#pragma unroll
    for (int it = 0; it < 6; ++it) {
      int s = sl + it * 64;
      if (s < 324) {
        int row = s / 18, col = s - row * 18;
        int yy = y0 + row, xx = x0 + col;
        float v0 = 0, v1 = 0, v2 = 0, v3 = 0;
        if ((unsigned)yy < 256u && (unsigned)xx < 256u) {
          const float* p = bp + yy * 256 + xx;
          v0 = p[0]; v1 = p[65536]; v2 = p[131072]; v3 = p[196608];
        }
        int slot = (q >> 1) ^ (s & 3) ^ ((s >> 2) & 3);
        *(s16x4*)&xt[s * 32 + slot * 8 + (q & 1) * 4] = pk4(v0, v1, v2, v3);
      }
    }
  }
  __syncthreads();

  int wv = tid >> 6, lane = tid & 63;
  int lr = lane & 15, lg = lane >> 4;

  // fused patch means: wave wv -> channels wv*4..wv*4+3; p = pp*64+lane
#pragma unroll
  for (int cc = 0; cc < 4; ++cc) {
    int c = wv * 4 + cc;
    int q = c >> 2, jj = c & 3;
    float s = 0.f;
#pragma unroll
    for (int pp = 0; pp < 4; ++pp) {
      int p = pp * 64 + lane;
      int sp = ((p >> 4) + 1) * 18 + (p & 15) + 1;
      int off = sp * 32 + (((q >> 1) ^ (sp & 3) ^ ((sp >> 2) & 3)) << 3) + (q & 1) * 4 + jj;
      s += bf2f(xt[off]);
    }
    for (int m = 1; m < 64; m <<= 1) s += __shfl_xor(s, m);
    if (lane == 0) nodes[(size_t)blk * 34 + c] = s * (1.f / 256.f);
  }
  if (tid == 0) {
    nodes[(size_t)blk * 34 + 32] = (float)gy * (1.f / 16.f);
    nodes[(size_t)blk * 34 + 33] = (float)gx * (1.f / 16.f);
  }

  // MFMA: A=weights (LDS), B=pixels. Wave wv covers rows wv*2, wv*2+1.
  f32x4 acc[2][2];
  f32x4 cb0 = *(const f32x4*)&conv_b[lg * 4];
  f32x4 cb1 = *(const f32x4*)&conv_b[16 + lg * 4];
#pragma unroll
  for (int mi = 0; mi < 2; ++mi) { acc[mi][0] = cb0; acc[mi][1] = cb1; }
#pragma unroll
  for (int tap = 0; tap < 9; ++tap) {
    s16x8 wf0 = *(const s16x8*)&wl[tap * 1024 + lane * 8];
    s16x8 wf1 = *(const s16x8*)&wl[tap * 1024 + 512 + lane * 8];
    int ky = tap / 3, kx = tap - ky * 3;
#pragma unroll
    for (int mi = 0; mi < 2; ++mi) {
      int s = (wv * 2 + mi + ky) * 18 + lr + kx;
      int offB = s * 32 + ((lg ^ (s & 3) ^ ((s >> 2) & 3)) << 3);
      s16x8 xf = *(const s16x8*)&xt[offB];
      acc[mi][0] = __builtin_amdgcn_mfma_f32_16x16x32_bf16(wf0, xf, acc[mi][0], 0, 0, 0);
      acc[mi][1] = __builtin_amdgcn_mfma_f32_16x16x32_bf16(wf1, xf, acc[mi][1], 0, 0, 0);
    }
  }
  // epilogue: channel-last store
#pragma unroll
  for (int mi = 0; mi < 2; ++mi) {
    int oy = gy * 16 + wv * 2 + mi;
    size_t pixbase = ((size_t)b * 65536 + (size_t)oy * 256 + gx * 16 + lr) * 32;
#pragma unroll
    for (int nt = 0; nt < 2; ++nt) {
      f32x4 a = acc[mi][nt];
      *(s16x4*)&ycl[pixbase + nt * 16 + lg * 4] = pk4(a[0], a[1], a[2], a[3]);
    }
  }
  // fused GN stats — gpart overlaid on xt
  __syncthreads();
  float* gpart = (float*)xt;
#pragma unroll
  for (int nt = 0; nt < 2; ++nt) {
    float s = 0.f, q = 0.f;
#pragma unroll
    for (int mi = 0; mi < 2; ++mi)
#pragma unroll
      for (int rr = 0; rr < 4; ++rr) {
        float v = acc[mi][nt][rr];
        s += v; q += v * v;
      }
    for (int m = 1; m < 16; m <<= 1) { s += __shfl_xor(s, m); q += __shfl_xor(q, m); }
    if (lr == 0) {
      int g = nt * 4 + lg;
      gpart[(g * 2 + 0) * 8 + wv] = s;
      gpart[(g * 2 + 1) * 8 + wv] = q;
    }
  }
  __syncthreads();
  if (tid < 16) {
    int g = tid >> 1, which = tid & 1;
    float v = 0.f;
#pragma unroll
    for (int w = 0; w < 8; ++w) v += gpart[(g * 2 + which) * 8 + w];
    atomicAdd(&stats[(which ? 128 : 0) + b * 8 + g], v);
  }
}

// K2: fold GN into per-(b,c) scale/shift
__global__ void gn_finalize(const float* __restrict__ stats,
                            const float* __restrict__ gn_g,
                            const float* __restrict__ gn_b,
                            float* __restrict__ mrs) {
  int i = threadIdx.x;  // 512
  int b = i >> 5, c = i & 31, g = c >> 2;
  float s = stats[b * 8 + g], q = stats[128 + b * 8 + g];
  const float n = 262144.f;
  float mean = s / n;
  float var = q / n - mean * mean;
  float rs = rsqrtf(var + 1e-5f);
  float scale = rs * gn_g[c];
  mrs[i] = scale;
  mrs[512 + i] = gn_b[c] - mean * scale;
}

__device__ __forceinline__ float dinv_at(int gy, int gx) {
  return rsqrtf((float)(1 + (gy > 0) + (gy < 15) + (gx > 0) + (gx < 15)));
}

// K3: fused GCN
__global__ __launch_bounds__(64) void gcn_fused(const float* __restrict__ nodes,
                                                const float* __restrict__ gw,
                                                const float* __restrict__ gcn_b,
                                                const float* __restrict__ ln_g,
                                                const float* __restrict__ ln_b,
                                                float* __restrict__ lnout) {
  int n = blockIdx.x * 2 + (threadIdx.x >> 5);
  int o = threadIdx.x & 31;
  int r = n & 255, gy = r >> 4, gx = r & 15;
  float dn = dinv_at(gy, gx);
  float s = 0.f;
  {
    const float* nr = nodes + (size_t)n * 34;
    float hh = 0.f;
#pragma unroll
    for (int k = 0; k < 34; ++k) hh = fmaf(nr[k], gw[k * 32 + o], hh);
    s = hh * dn;
  }
  if (gy > 0) {
    const float* nr = nodes + (size_t)(n - 16) * 34;
    float hh = 0.f;
#pragma unroll
    for (int k = 0; k < 34; ++k) hh = fmaf(nr[k], gw[k * 32 + o], hh);
    s += hh * dinv_at(gy - 1, gx);
  }
  if (gy < 15) {
    const float* nr = nodes + (size_t)(n + 16) * 34;
    float hh = 0.f;
#pragma unroll
    for (int k = 0; k < 34; ++k) hh = fmaf(nr[k], gw[k * 32 + o], hh);
    s += hh * dinv_at(gy + 1, gx);
  }
  if (gx > 0) {
    const float* nr = nodes + (size_t)(n - 1) * 34;
    float hh = 0.f;
#pragma unroll
    for (int k = 0; k < 34; ++k) hh = fmaf(nr[k], gw[k * 32 + o], hh);
    s += hh * dinv_at(gy, gx - 1);
  }
  if (gx < 15) {
    const float* nr = nodes + (size_t)(n + 1) * 34;
    float hh = 0.f;
#pragma unroll
    for (int k = 0; k < 34; ++k) hh = fmaf(nr[k], gw[k * 32 + o], hh);
    s += hh * dinv_at(gy, gx + 1);
  }
  float g = dn * s + gcn_b[o];
  float mu = g;
  for (int m = 16; m; m >>= 1) mu += __shfl_xor(mu, m);
  mu *= (1.0f / 32.0f);
  float d = g - mu;
  float v = d * d;
  for (int m = 16; m; m >>= 1) v += __shfl_xor(v, m);
  v *= (1.0f / 32.0f);
  lnout[n * 32 + o] = d * rsqrtf(v + 1e-5f) * ln_g[o] + ln_b[o];
}

// K6: k-split 2-phase gate conv, 512 threads; comb = LINEAR pad-80B layout
// (row stride 40 u16: bank-quad walk (5s)%8 covers all 8 quads -> conflict-free,
// zero swizzle arithmetic). Gate sigmoid via prescaled weights + exp2.
__global__ __launch_bounds__(512) void fused_gate_mfma(
    const unsigned short* __restrict__ ycl, const float* __restrict__ mrs,
    const float* __restrict__ lnf, const unsigned short* __restrict__ wgF,
    const float* __restrict__ gbs, const float* __restrict__ tpv,
    float* __restrict__ out) {
  __shared__ alignas(16) unsigned short comb[324 * 40];   // 25.9KB, linear pad-80B
  __shared__ alignas(16) unsigned short vvb[18 * 3 * 32]; // 3.4KB
  __shared__ alignas(16) unsigned short wl[9216];         // 18KB per-phase weights
  int blk = xcd_swz(blockIdx.x);
  int b = blk >> 8, r = blk & 255, gy = r >> 4, gx = r & 15;
  int tid = threadIdx.x;
  int wv = tid >> 6, lane = tid & 63;
  int lr = lane & 15, lg = lane >> 4;
  int y0 = gy * 16 - 1, x0 = gx * 16 - 1;
  const s16x8 z8 = (s16x8){0, 0, 0, 0, 0, 0, 0, 0};

  // ---- phase A staging: weights(p0) + conv half + vvb ----
  for (int i = tid; i < 1152; i += 512)
    *(s16x8*)&wl[i * 8] = *(const s16x8*)&wgF[i * 8];

  int row0 = tid / 18, col0 = tid - row0 * 18;
  int yy0_ = y0 + row0, xx0_ = x0 + col0;
  bool act = tid < 324;
  bool in0 = act && ((unsigned)yy0_ < 256u) && ((unsigned)xx0_ < 256u);
  const unsigned short* p0 = ycl + ((size_t)b * 65536 + (size_t)yy0_ * 256 + xx0_) * 32;
  s16x8 v0[4];
#pragma unroll
  for (int h = 0; h < 4; ++h) v0[h] = in0 ? *(const s16x8*)&p0[h * 8] : z8;

  for (int i = tid; i < 1728; i += 512) {
    int row = i / 96, rem = i - row * 96, xc = rem >> 5, c = rem & 31;
    int yy = y0 + row;
    float uy = ((float)yy + 0.5f) * (1.f / 16.f) - 0.5f;
    float fy = floorf(uy);
    float ty = uy - fy;
    int iy0 = (int)fy;
    int iy0c = max(0, iy0), iy1c = min(15, iy0 + 1);
    int gxx = min(15, max(0, gx - 1 + xc));
    const float* base = lnf + (size_t)b * 8192 + c * 256;
    float a0 = base[iy0c * 16 + gxx], a1 = base[iy1c * 16 + gxx];
    vvb[i] = f2bf(a0 + ty * (a1 - a0));
  }

  if (act) {
#pragma unroll
    for (int h = 0; h < 4; ++h) {
      float f0[8];
#pragma unroll
      for (int j = 0; j < 8; ++j) {
        float sc = mrs[b * 32 + h * 8 + j];
        float sh = mrs[512 + b * 32 + h * 8 + j];
        float a = bf2f((unsigned short)v0[h][j]) * sc + sh;
        f0[j] = a * sigmoidf_(a);
      }
      *(s16x8*)&comb[tid * 40 + h * 8] = pk8(f0);
    }
  }
  __syncthreads();  // barrier 1

  // ---- phase A MFMA: ic 0..31 ----
  f32x4 acc[2][2];
  float b0 = gbs[lr], b1 = gbs[16 + lr];
#pragma unroll
  for (int mi = 0; mi < 2; ++mi) {
    acc[mi][0] = (f32x4){b0, b0, b0, b0};
    acc[mi][1] = (f32x4){b1, b1, b1, b1};
  }
#pragma unroll
  for (int tap = 0; tap < 9; ++tap) {
    s16x8 wlo = *(const s16x8*)&wl[tap * 1024 + lane * 8];
    s16x8 whi = *(const s16x8*)&wl[tap * 1024 + 512 + lane * 8];
    int ky = tap / 3, kx = tap - ky * 3;
#pragma unroll
    for (int mi = 0; mi < 2; ++mi) {
      int s = (wv * 2 + mi + ky) * 18 + lr + kx;
      s16x8 a = *(const s16x8*)&comb[s * 40 + lg * 8];
      acc[mi][0] = __builtin_amdgcn_mfma_f32_16x16x32_bf16(a, wlo, acc[mi][0], 0, 0, 0);
      acc[mi][1] = __builtin_amdgcn_mfma_f32_16x16x32_bf16(a, whi, acc[mi][1], 0, 0, 0);
    }
  }

  // save cf centers before comb is overwritten (linear layout)
  unsigned cfp[2][2][2];
#pragma unroll
  for (int mi = 0; mi < 2; ++mi) {
    int m = wv * 2 + mi;
#pragma unroll
    for (int nt = 0; nt < 2; ++nt) {
      int oct = nt * 2 + (lr >> 3), el = lr & 7;
#pragma unroll
      for (int rh = 0; rh < 2; ++rh) {
        int px0 = lg * 4 + rh * 2, px1 = px0 + 1;
        int s0 = (m + 1) * 18 + px0 + 1, s1 = (m + 1) * 18 + px1 + 1;
        unsigned lo = comb[s0 * 40 + oct * 8 + el];
        unsigned hi = comb[s1 * 40 + oct * 8 + el];
        cfp[mi][nt][rh] = lo | (hi << 16);
      }
    }
  }
  __syncthreads();  // barrier 2

  // ---- phase B staging: weights(p1) + gcn half ----
  for (int i = tid; i < 1152; i += 512)
    *(s16x8*)&wl[i * 8] = *(const s16x8*)&wgF[9216 + i * 8];

  if (act) {
    if (((unsigned)yy0_ < 256u) && ((unsigned)xx0_ < 256u)) {
      float ux = ((float)xx0_ + 0.5f) * (1.f / 16.f) - 0.5f;
      float fx = floorf(ux);
      float tx = ux - fx;
      int dx0 = (int)fx - (gx - 1);   // in {0,1}
      const unsigned short* va = &vvb[(row0 * 3 + dx0) * 32];
      const unsigned short* vb = va + 32;
#pragma unroll
      for (int h = 0; h < 4; ++h) {
        s16x8 av = *(const s16x8*)&va[h * 8];
        s16x8 bv = *(const s16x8*)&vb[h * 8];
        float f[8];
#pragma unroll
        for (int j = 0; j < 8; ++j) {
          float a = bf2f((unsigned short)av[j]);
          f[j] = a + tx * (bf2f((unsigned short)bv[j]) - a);
        }
        *(s16x8*)&comb[tid * 40 + h * 8] = pk8(f);
      }
    } else {
#pragma unroll
      for (int h = 0; h < 4; ++h) *(s16x8*)&comb[tid * 40 + h * 8] = z8;
    }
  }
  __syncthreads();  // barrier 3

  // ---- phase B MFMA: ic 32..63 ----
#pragma unroll
  for (int tap = 0; tap < 9; ++tap) {
    s16x8 wlo = *(const s16x8*)&wl[tap * 1024 + lane * 8];
    s16x8 whi = *(const s16x8*)&wl[tap * 1024 + 512 + lane * 8];
    int ky = tap / 3, kx = tap - ky * 3;
#pragma unroll
    for (int mi = 0; mi < 2; ++mi) {
      int s = (wv * 2 + mi + ky) * 18 + lr + kx;
      s16x8 a = *(const s16x8*)&comb[s * 40 + lg * 8];
      acc[mi][0] = __builtin_amdgcn_mfma_f32_16x16x32_bf16(a, wlo, acc[mi][0], 0, 0, 0);
      acc[mi][1] = __builtin_amdgcn_mfma_f32_16x16x32_bf16(a, whi, acc[mi][1], 0, 0, 0);
    }
  }

  // ---- epilogue: gate = 1/(1+2^z') (weights prescaled by -log2e) ----
#pragma unroll
  for (int mi = 0; mi < 2; ++mi) {
    int m = wv * 2 + mi;
#pragma unroll
    for (int nt = 0; nt < 2; ++nt) {
      int o = nt * 16 + lr;
      int oct = nt * 2 + (lr >> 3), el = lr & 7;
      f32x4 a = acc[mi][nt];
      float gamma = tpv[b * 64 + o] + 1.0f, beta = tpv[b * 64 + 32 + o];
      f32x4 res;
#pragma unroll
      for (int rr = 0; rr < 4; ++rr) {
        int px = lg * 4 + rr;
        int s = (m + 1) * 18 + px + 1;
        unsigned cfu = cfp[mi][nt][rr >> 1];
        float cf = bf2f((unsigned short)((rr & 1) ? (cfu >> 16) : (cfu & 0xffff)));
        float gu = bf2f(comb[s * 40 + oct * 8 + el]);
        float gate = 1.0f / (1.0f + exp2f(a[rr]));
        float merged = gu + gate * (cf - gu);
        res[rr] = merged * gamma + beta;
      }
      *(f32x4*)&out[((size_t)(b * 32 + o)) * 65536 + (size_t)(gy * 16 + m) * 256 + gx * 16 + lg * 4] = res;
    }
  }
}

extern "C" void kernel_launch(void* const* d_in, const int* in_sizes, int n_in,
                              void* d_out, int out_size, void* d_ws, size_t ws_size,
                              hipStream_t stream) {
  const float* x      = (const float*)d_in[0];
  const float* t      = (const float*)d_in[1];
  const float* conv_w = (const float*)d_in[2];
  const float* conv_b = (const float*)d_in[3];
  const float* gn_g   = (const float*)d_in[4];
  const float* gn_b   = (const float*)d_in[5];
  const float* gcn_w  = (const float*)d_in[6];
  const float* gcn_b  = (const float*)d_in[7];
  const float* ln_g   = (const float*)d_in[8];
  const float* ln_b   = (const float*)d_in[9];
  const float* gate_w = (const float*)d_in[10];
  const float* gate_b = (const float*)d_in[11];
  const float* tp_w   = (const float*)d_in[12];
  const float* tp_b   = (const float*)d_in[13];

  float* ws = (float*)d_ws;
  unsigned short* ycl = (unsigned short*)ws;        // 33,554,432 u16
  float* st    = ws + 16777216;                     // 256
  float* mrs   = st + 256;                          // 1024
  float* nodes = mrs + 1024;                        // 139,264
  float* lnf   = nodes + 139264;                    // 131,072
  float* tpv   = lnf + 131072;                      // 1,024
  unsigned short* wcF = (unsigned short*)(tpv + 1024);   // 9,216 u16
  unsigned short* wgF = wcF + 9216;                 // 18,432 u16
  float* gbs   = (float*)(wgF + 18432);             // 32

  hipMemsetAsync(st, 0, 256 * sizeof(float), stream);
  prep_misc<<<76, 256, 0, stream>>>(conv_w, gate_w, t, tp_w, tp_b, gate_b,
                                    wcF, wgF, tpv, gbs);
  conv1_mfma<<<4096, 512, 0, stream>>>(x, wcF, conv_b, ycl, st, nodes);
  gn_finalize<<<1, 512, 0, stream>>>(st, gn_g, gn_b, mrs);
  gcn_fused<<<2048, 64, 0, stream>>>(nodes, gcn_w, gcn_b, ln_g, ln_b, lnf);
  fused_gate_mfma<<<4096, 512, 0, stream>>>(ycl, mrs, lnf, wgF, gbs, tpv,
                                            (float*)d_out);
}